// Round 11
// baseline (215.722 us; speedup 1.0000x reference)
//
#include <hip/hip_runtime.h>

#define EPSN   1e-8f
#define MARGIN 0.2f
#define ALPHA  0.1f
#define BETA   1.05f
#define DIM    512
#define NCLS   16

typedef __attribute__((ext_vector_type(8))) short short8;
typedef __attribute__((ext_vector_type(4))) float f32x4;
typedef __attribute__((ext_vector_type(4))) float nf4;   // native vec for nontemporal builtins

__device__ __forceinline__ unsigned short f2bf(float f) {
    unsigned u = __float_as_uint(f);
    return (unsigned short)((u + 0x7FFFu + ((u >> 16) & 1u)) >> 16);  // RNE
}
__device__ __forceinline__ short8 pack8(float4 x0, float4 x1) {
    short8 r;
    r[0] = (short)f2bf(x0.x); r[1] = (short)f2bf(x0.y);
    r[2] = (short)f2bf(x0.z); r[3] = (short)f2bf(x0.w);
    r[4] = (short)f2bf(x1.x); r[5] = (short)f2bf(x1.y);
    r[6] = (short)f2bf(x1.z); r[7] = (short)f2bf(x1.w);
    return r;
}

// ws layout (f32 words):
//     0: sums[8192]        8192: cpart i32[64][16]   9216: scal[8] ([0]tri [1]intra [2]inter)
//  9224: done u32          9225: done2 u32           9232: ncn[8192]
// 17424: pr[256]          17680: cf[16]             17696: ntv[2] ([0]=n_terms [1]=1/max(nt,1))

// ---------------- Kernel 0: init = zero accumulators + label histogram partials ----------------
__global__ __launch_bounds__(256) void k_init(const int* __restrict__ L,
                                              float* __restrict__ wsw,
                                              int* __restrict__ cpart, int N) {
    __shared__ int hist[NCLS];
    int t = threadIdx.x, bid = blockIdx.x;
    int gid = bid * 256 + t;
    for (int i = gid; i < 8192; i += 64 * 256) wsw[i] = 0.f;
    if (gid < 16) wsw[9216 + gid] = 0.f;   // scal + done + done2
    if (t < NCLS) hist[t] = 0;
    __syncthreads();
    int chunk = N >> 6;
    int base = bid * chunk;
    for (int i = t * 4; i < chunk; i += 1024) {
        int4 l4 = *(const int4*)(L + base + i);
        atomicAdd(&hist[l4.x], 1);
        atomicAdd(&hist[l4.y], 1);
        atomicAdd(&hist[l4.z], 1);
        atomicAdd(&hist[l4.w], 1);
    }
    __syncthreads();
    if (t < NCLS) cpart[bid * NCLS + t] = hist[t];
}

// ---------------- Kernel 1: triplet loss partial sum -> scal[0] ----------------
// R5-proven: nt loads (skip L3 alloc), 2-deep pipeline, coalesced 256B chunks.
__global__ __launch_bounds__(256) void k_triplet(const float* __restrict__ A,
                                                 const float* __restrict__ P,
                                                 const float* __restrict__ Q,
                                                 float* __restrict__ scal, int N) {
    __shared__ float red[4];
    int t = threadIdx.x, lane = t & 63, wid = t >> 6;
    int g = lane >> 4, seg = lane & 15;
    int gw = blockIdx.x * 4 + wid, nw = gridDim.x * 4;
    int nquad = N >> 2;
    float tri = 0.f;
    for (int quad = gw; quad < nquad; quad += 2 * nw) {
        int quadB = quad + nw;
        bool hasB = quadB < nquad;
        size_t base0 = (size_t)(quad * 4 + g) * DIM + seg * 4;
        size_t base1 = hasB ? ((size_t)(quadB * 4 + g) * DIM + seg * 4) : base0;
        nf4 a0[8], p0[8], q0[8], a1[8], p1[8], q1[8];
#pragma unroll
        for (int i = 0; i < 8; ++i) a0[i] = __builtin_nontemporal_load((const nf4*)(A + base0 + i * 64));
#pragma unroll
        for (int i = 0; i < 8; ++i) p0[i] = __builtin_nontemporal_load((const nf4*)(P + base0 + i * 64));
#pragma unroll
        for (int i = 0; i < 8; ++i) q0[i] = __builtin_nontemporal_load((const nf4*)(Q + base0 + i * 64));
#pragma unroll
        for (int i = 0; i < 8; ++i) a1[i] = __builtin_nontemporal_load((const nf4*)(A + base1 + i * 64));
#pragma unroll
        for (int i = 0; i < 8; ++i) p1[i] = __builtin_nontemporal_load((const nf4*)(P + base1 + i * 64));
#pragma unroll
        for (int i = 0; i < 8; ++i) q1[i] = __builtin_nontemporal_load((const nf4*)(Q + base1 + i * 64));
        {
            float sa = 0, sp = 0, sn = 0, dap = 0, dan = 0;
#pragma unroll
            for (int i = 0; i < 8; ++i) {
                sa  = fmaf(a0[i].x,a0[i].x, fmaf(a0[i].y,a0[i].y, fmaf(a0[i].z,a0[i].z, fmaf(a0[i].w,a0[i].w, sa))));
                sp  = fmaf(p0[i].x,p0[i].x, fmaf(p0[i].y,p0[i].y, fmaf(p0[i].z,p0[i].z, fmaf(p0[i].w,p0[i].w, sp))));
                sn  = fmaf(q0[i].x,q0[i].x, fmaf(q0[i].y,q0[i].y, fmaf(q0[i].z,q0[i].z, fmaf(q0[i].w,q0[i].w, sn))));
                dap = fmaf(a0[i].x,p0[i].x, fmaf(a0[i].y,p0[i].y, fmaf(a0[i].z,p0[i].z, fmaf(a0[i].w,p0[i].w, dap))));
                dan = fmaf(a0[i].x,q0[i].x, fmaf(a0[i].y,q0[i].y, fmaf(a0[i].z,q0[i].z, fmaf(a0[i].w,q0[i].w, dan))));
            }
#pragma unroll
            for (int o = 1; o < 16; o <<= 1) {
                sa  += __shfl_xor(sa,  o);
                sp  += __shfl_xor(sp,  o);
                sn  += __shfl_xor(sn,  o);
                dap += __shfl_xor(dap, o);
                dan += __shfl_xor(dan, o);
            }
            if (seg == 0) {
                float na = fmaxf(sqrtf(sa), EPSN);
                float np = fmaxf(sqrtf(sp), EPSN);
                float nn = fmaxf(sqrtf(sn), EPSN);
                tri += fmaxf((1.f - dap / (na * np)) - (1.f - dan / (na * nn)) + MARGIN, 0.f);
            }
        }
        if (hasB) {
            float sa = 0, sp = 0, sn = 0, dap = 0, dan = 0;
#pragma unroll
            for (int i = 0; i < 8; ++i) {
                sa  = fmaf(a1[i].x,a1[i].x, fmaf(a1[i].y,a1[i].y, fmaf(a1[i].z,a1[i].z, fmaf(a1[i].w,a1[i].w, sa))));
                sp  = fmaf(p1[i].x,p1[i].x, fmaf(p1[i].y,p1[i].y, fmaf(p1[i].z,p1[i].z, fmaf(p1[i].w,p1[i].w, sp))));
                sn  = fmaf(q1[i].x,q1[i].x, fmaf(q1[i].y,q1[i].y, fmaf(q1[i].z,q1[i].z, fmaf(q1[i].w,q1[i].w, sn))));
                dap = fmaf(a1[i].x,p1[i].x, fmaf(a1[i].y,p1[i].y, fmaf(a1[i].z,p1[i].z, fmaf(a1[i].w,p1[i].w, dap))));
                dan = fmaf(a1[i].x,q1[i].x, fmaf(a1[i].y,q1[i].y, fmaf(a1[i].z,q1[i].z, fmaf(a1[i].w,q1[i].w, dan))));
            }
#pragma unroll
            for (int o = 1; o < 16; o <<= 1) {
                sa  += __shfl_xor(sa,  o);
                sp  += __shfl_xor(sp,  o);
                sn  += __shfl_xor(sn,  o);
                dap += __shfl_xor(dap, o);
                dan += __shfl_xor(dan, o);
            }
            if (seg == 0) {
                float na = fmaxf(sqrtf(sa), EPSN);
                float np = fmaxf(sqrtf(sp), EPSN);
                float nn = fmaxf(sqrtf(sn), EPSN);
                tri += fmaxf((1.f - dap / (na * np)) - (1.f - dan / (na * nn)) + MARGIN, 0.f);
            }
        }
    }
    tri += __shfl_xor(tri, 16);
    tri += __shfl_xor(tri, 32);
    if (lane == 0) red[wid] = tri;
    __syncthreads();
    if (t == 0) atomicAdd(&scal[0], red[0] + red[1] + red[2] + red[3]);
}

// ---------------- Kernel 2: per-class sums + LAST-BLOCK centroid/pair/cnt tail ----------------
// Main: column-half split, 16KB LDS, thread-exclusive column slot.
// Tail (last block via done2): counts from cpart, ncn normalize -> global,
// fp32 pair matrix (global L2 reads), cf row-sums, n_terms.
__global__ __launch_bounds__(256) void k_segsum(const float* __restrict__ E,
                                                const int* __restrict__ L,
                                                const int* __restrict__ cpart,
                                                float* __restrict__ wsf,
                                                unsigned* __restrict__ done2, int N) {
    __shared__ float acc[NCLS * 256];    // exactly 16 KB
    __shared__ float cntl[NCLS];
    __shared__ float prs[NCLS * NCLS];
    __shared__ int lastFlag;
    int t = threadIdx.x;
    int half = blockIdx.x & 1;
    int rg = blockIdx.x >> 1;
    int rpg = N >> 9;
    int r0 = rg * rpg;
    float* sums = wsf;
    for (int i = t; i < NCLS * 256; i += 256) acc[i] = 0.f;
    __syncthreads();
    const float* Eh = E + half * 256 + t;
    for (int r = r0; r < r0 + rpg; r += 16) {
        int l[16];
        float v[16];
#pragma unroll
        for (int i = 0; i < 16; ++i) l[i] = L[r + i];
#pragma unroll
        for (int i = 0; i < 16; ++i) v[i] = Eh[(size_t)(r + i) * DIM];
#pragma unroll
        for (int i = 0; i < 16; ++i) acc[l[i] * 256 + t] += v[i];
    }
    __syncthreads();
#pragma unroll
    for (int c = 0; c < NCLS; ++c)
        atomicAdd(&sums[c * DIM + half * 256 + t], acc[c * 256 + t]);
    __syncthreads();
    if (t == 0) {
        __threadfence();
        lastFlag = (atomicAdd(done2, 1u) == gridDim.x - 1) ? 1 : 0;
    }
    __syncthreads();
    if (!lastFlag) return;

    // ---- tail: runs once, on the last block ----
    __threadfence();                       // see all blocks' sums
    float* ncn = wsf + 9232;
    float* prw = wsf + 17424;
    float* cfw = wsf + 17680;
    float* ntv = wsf + 17696;
    if (t < NCLS) {
        int s = 0;
        for (int b = 0; b < 64; ++b) s += cpart[b * NCLS + t];
        cntl[t] = (float)s;
    }
    __syncthreads();
    {   // centroids -> global ncn
        int c = t >> 4, sI = t & 15;
        float inv = 1.f / fmaxf(cntl[c], 1.f);
        float4 v[8];
        float ssq = 0.f;
#pragma unroll
        for (int i = 0; i < 8; ++i) {
            v[i] = *(const float4*)(sums + c * DIM + sI * 32 + i * 4);
            v[i].x *= inv; v[i].y *= inv; v[i].z *= inv; v[i].w *= inv;
            ssq = fmaf(v[i].x, v[i].x, fmaf(v[i].y, v[i].y, fmaf(v[i].z, v[i].z, fmaf(v[i].w, v[i].w, ssq))));
        }
#pragma unroll
        for (int o = 1; o < 16; o <<= 1) ssq += __shfl_xor(ssq, o);
        float rs = 1.f / fmaxf(sqrtf(ssq), EPSN);
#pragma unroll
        for (int i = 0; i < 8; ++i) {
            float4 w = v[i];
            w.x *= rs; w.y *= rs; w.z *= rs; w.w *= rs;
            *(float4*)(ncn + c * DIM + sI * 32 + i * 4) = w;
        }
    }
    __syncthreads();
    __threadfence_block();
    {   // fp32 pair matrix from global ncn (L2-hot, just written by this block)
        int i = t >> 4, j = t & 15;
        float dot = 0.f;
        for (int dd = 0; dd < DIM; dd += 32) {
            float4 av[8], bv[8];
#pragma unroll
            for (int k = 0; k < 8; ++k) av[k] = *(const float4*)(ncn + i * DIM + dd + k * 4);
#pragma unroll
            for (int k = 0; k < 8; ++k) bv[k] = *(const float4*)(ncn + j * DIM + dd + k * 4);
#pragma unroll
            for (int k = 0; k < 8; ++k)
                dot = fmaf(av[k].x, bv[k].x, fmaf(av[k].y, bv[k].y, fmaf(av[k].z, bv[k].z, fmaf(av[k].w, bv[k].w, dot))));
        }
        float cd = 1.f - dot;
        float pf = (cd <= BETA && i != j && cntl[i] > 0.f && cntl[j] > 0.f) ? 1.f : 0.f;
        prs[t] = pf;
        prw[t] = pf;
    }
    __syncthreads();
    if (t < NCLS) {
        float s = 0.f;
#pragma unroll
        for (int k = 0; k < NCLS; ++k) s += prs[t * 16 + k];
        cfw[t] = s;
        cntl[t] = cntl[t] * s;   // contribution to n_terms
    }
    __syncthreads();
    if (t == 0) {
        float nt = 0.f;
#pragma unroll
        for (int k = 0; k < NCLS; ++k) nt += cntl[k];
        ntv[0] = nt;
        ntv[1] = 1.f / fmaxf(nt, 1.f);
    }
}

// ---------------- Kernel 3: ATN main loop (no prologue) + last-block final ----------------
// bfr from global ncn (L2-hot); 8-load burst groups for MLP; 4 MFMA/ss chains.
__global__ __launch_bounds__(256, 4) void k_atn(const float* __restrict__ E,
                                                const int* __restrict__ L,
                                                const float* __restrict__ ncn,
                                                const float* __restrict__ pr_g,
                                                const float* __restrict__ cf_g,
                                                const float* __restrict__ ntv,
                                                float* __restrict__ scal,
                                                unsigned* __restrict__ done,
                                                float* __restrict__ out,
                                                float invN, int N) {
    __shared__ float pr[NCLS * NCLS];
    __shared__ float cf[NCLS];
    __shared__ float red[8];
    int t = threadIdx.x, lane = t & 63, wid = t >> 6;
    pr[t] = pr_g[t];
    if (t < NCLS) cf[t] = cf_g[t];
    __syncthreads();

    int col = lane & 15;      // A-row within tile == B-col (class)
    int kg = lane >> 4;       // k-group 0..3
    short8 bfr[16];
#pragma unroll
    for (int s = 0; s < 16; ++s) {
        float4 q0 = *(const float4*)(ncn + col * DIM + s * 32 + kg * 8);
        float4 q1 = *(const float4*)(ncn + col * DIM + s * 32 + kg * 8 + 4);
        bfr[s] = pack8(q0, q1);
    }

    float inter = 0.f, intra = 0.f;
    int gw = blockIdx.x * 4 + wid, nw = gridDim.x * 4;
    int ntile = N >> 4;
    for (int tile = gw; tile < ntile; tile += nw) {
        int rowb = tile << 4;
        const float* ar = E + (size_t)(rowb + col) * DIM + kg * 8;
        f32x4 ac0 = {0,0,0,0}, ac1 = {0,0,0,0}, ac2 = {0,0,0,0}, ac3 = {0,0,0,0};
        float ss0 = 0.f, ss1 = 0.f, ss2 = 0.f, ss3 = 0.f;
#pragma unroll
        for (int sg = 0; sg < 4; ++sg) {
            float4 x[8];
#pragma unroll
            for (int k = 0; k < 8; ++k)
                x[k] = *(const float4*)(ar + sg * 128 + (k >> 1) * 32 + (k & 1) * 4);
            // s = sg*4 + k2; chains k2 = 0..3
            {
                float4 u = x[0], v = x[1];
                ss0 = fmaf(u.x,u.x, fmaf(u.y,u.y, fmaf(u.z,u.z, fmaf(u.w,u.w, ss0))));
                ss0 = fmaf(v.x,v.x, fmaf(v.y,v.y, fmaf(v.z,v.z, fmaf(v.w,v.w, ss0))));
                ac0 = __builtin_amdgcn_mfma_f32_16x16x32_bf16(pack8(u, v), bfr[sg * 4 + 0], ac0, 0, 0, 0);
            }
            {
                float4 u = x[2], v = x[3];
                ss1 = fmaf(u.x,u.x, fmaf(u.y,u.y, fmaf(u.z,u.z, fmaf(u.w,u.w, ss1))));
                ss1 = fmaf(v.x,v.x, fmaf(v.y,v.y, fmaf(v.z,v.z, fmaf(v.w,v.w, ss1))));
                ac1 = __builtin_amdgcn_mfma_f32_16x16x32_bf16(pack8(u, v), bfr[sg * 4 + 1], ac1, 0, 0, 0);
            }
            {
                float4 u = x[4], v = x[5];
                ss2 = fmaf(u.x,u.x, fmaf(u.y,u.y, fmaf(u.z,u.z, fmaf(u.w,u.w, ss2))));
                ss2 = fmaf(v.x,v.x, fmaf(v.y,v.y, fmaf(v.z,v.z, fmaf(v.w,v.w, ss2))));
                ac2 = __builtin_amdgcn_mfma_f32_16x16x32_bf16(pack8(u, v), bfr[sg * 4 + 2], ac2, 0, 0, 0);
            }
            {
                float4 u = x[6], v = x[7];
                ss3 = fmaf(u.x,u.x, fmaf(u.y,u.y, fmaf(u.z,u.z, fmaf(u.w,u.w, ss3))));
                ss3 = fmaf(v.x,v.x, fmaf(v.y,v.y, fmaf(v.z,v.z, fmaf(v.w,v.w, ss3))));
                ac3 = __builtin_amdgcn_mfma_f32_16x16x32_bf16(pack8(u, v), bfr[sg * 4 + 3], ac3, 0, 0, 0);
            }
        }
        f32x4 accv = (ac0 + ac1) + (ac2 + ac3);
        float ss = (ss0 + ss1) + (ss2 + ss3);
        ss += __shfl_xor(ss, 16);
        ss += __shfl_xor(ss, 32);
#pragma unroll
        for (int reg = 0; reg < 4; ++reg) {
            int row = kg * 4 + reg;            // C/D: col=lane&15, row=(lane>>4)*4+reg
            float s2 = __shfl(ss, row);
            float rinv = 1.f / fmaxf(sqrtf(s2), EPSN);
            float d = 1.f - accv[reg] * rinv;
            int lab = L[rowb + row];
            inter += pr[lab * 16 + col] * fmaxf(BETA - d, 0.f);
            if (col == lab) intra += cf[lab] * fmaxf(d - ALPHA, 0.f);
        }
    }
#pragma unroll
    for (int o = 32; o > 0; o >>= 1) {
        inter += __shfl_xor(inter, o);
        intra += __shfl_xor(intra, o);
    }
    if (lane == 0) { red[wid] = intra; red[4 + wid] = inter; }
    __syncthreads();
    if (t == 0) {
        atomicAdd(&scal[1], red[0] + red[1] + red[2] + red[3]);
        atomicAdd(&scal[2], red[4] + red[5] + red[6] + red[7]);
        __threadfence();
        unsigned old = atomicAdd(done, 1u);
        if (old == gridDim.x - 1) {
            __threadfence();
            float tri  = atomicAdd(&scal[0], 0.f);
            float intr = atomicAdd(&scal[1], 0.f);
            float inte = atomicAdd(&scal[2], 0.f);
            float nt = ntv[0];
            float atnv = (nt > 0.f) ? (intr + inte) * ntv[1] : 0.f;
            out[0] = tri * invN + atnv;
        }
    }
}

extern "C" void kernel_launch(void* const* d_in, const int* in_sizes, int n_in,
                              void* d_out, int out_size, void* d_ws, size_t ws_size,
                              hipStream_t stream) {
    const float* A = (const float*)d_in[0];
    const float* P = (const float*)d_in[1];
    const float* Q = (const float*)d_in[2];
    const float* E = (const float*)d_in[3];
    const int*   L = (const int*)d_in[4];
    int N = in_sizes[0] / DIM;

    float*    wsf   = (float*)d_ws;
    int*      cpart = (int*)(wsf + 8192);
    float*    scal  = wsf + 9216;
    unsigned* done  = (unsigned*)(wsf + 9224);
    unsigned* done2 = (unsigned*)(wsf + 9225);
    float*    ncn   = wsf + 9232;
    float*    prg   = wsf + 17424;
    float*    cfg   = wsf + 17680;
    float*    ntv   = wsf + 17696;

    k_init    <<<64,   256, 0, stream>>>(L, wsf, cpart, N);
    k_triplet <<<2048, 256, 0, stream>>>(A, P, Q, scal, N);
    k_segsum  <<<1024, 256, 0, stream>>>(E, L, cpart, wsf, done2, N);
    k_atn     <<<1024, 256, 0, stream>>>(E, L, ncn, prg, cfg, ntv, scal, done,
                                         (float*)d_out, 1.f / (float)N, N);
}

// Round 12
// 191.675 us; speedup vs baseline: 1.1255x; 1.1255x over previous
//
#include <hip/hip_runtime.h>

#define EPSN   1e-8f
#define MARGIN 0.2f
#define ALPHA  0.1f
#define BETA   1.05f
#define DIM    512
#define NCLS   16
#define NSTR   516   // padded LDS stride (2-way banks max, free per m136)

typedef __attribute__((ext_vector_type(8))) short short8;
typedef __attribute__((ext_vector_type(4))) float f32x4;
typedef __attribute__((ext_vector_type(4))) float nf4;

__device__ __forceinline__ unsigned short f2bf(float f) {
    unsigned u = __float_as_uint(f);
    return (unsigned short)((u + 0x7FFFu + ((u >> 16) & 1u)) >> 16);  // RNE
}
__device__ __forceinline__ short8 pack8(float4 x0, float4 x1) {
    short8 r;
    r[0] = (short)f2bf(x0.x); r[1] = (short)f2bf(x0.y);
    r[2] = (short)f2bf(x0.z); r[3] = (short)f2bf(x0.w);
    r[4] = (short)f2bf(x1.x); r[5] = (short)f2bf(x1.y);
    r[6] = (short)f2bf(x1.z); r[7] = (short)f2bf(x1.w);
    return r;
}

// ws layout (f32 words):
//     0: sums[8192]        8192: cpart i32[64][16]   9216: scal[8] ([0]tri [1]intra [2]inter)
//  9224: done u32          9232: ncn[8192]
// 17424: pr[256]          17680: cf[16]             17696: ntv[2]

// ---------------- Kernel 0: init = zero accumulators + label histogram partials ----------------
__global__ __launch_bounds__(256) void k_init(const int* __restrict__ L,
                                              float* __restrict__ wsw,
                                              int* __restrict__ cpart, int N) {
    __shared__ int hist[NCLS];
    int t = threadIdx.x, bid = blockIdx.x;
    int gid = bid * 256 + t;
    for (int i = gid; i < 8192; i += 64 * 256) wsw[i] = 0.f;
    if (gid < 16) wsw[9216 + gid] = 0.f;   // scal + done
    if (t < NCLS) hist[t] = 0;
    __syncthreads();
    int chunk = N >> 6;
    int base = bid * chunk;
    for (int i = t * 4; i < chunk; i += 1024) {
        int4 l4 = *(const int4*)(L + base + i);
        atomicAdd(&hist[l4.x], 1);
        atomicAdd(&hist[l4.y], 1);
        atomicAdd(&hist[l4.z], 1);
        atomicAdd(&hist[l4.w], 1);
    }
    __syncthreads();
    if (t < NCLS) cpart[bid * NCLS + t] = hist[t];
}

// ---------------- Kernel 1: triplet loss partial sum -> scal[0] ----------------
// R5-proven: nt loads, 2-deep pipeline, coalesced 256B chunks, 16-lane reduce.
__global__ __launch_bounds__(256) void k_triplet(const float* __restrict__ A,
                                                 const float* __restrict__ P,
                                                 const float* __restrict__ Q,
                                                 float* __restrict__ scal, int N) {
    __shared__ float red[4];
    int t = threadIdx.x, lane = t & 63, wid = t >> 6;
    int g = lane >> 4, seg = lane & 15;
    int gw = blockIdx.x * 4 + wid, nw = gridDim.x * 4;
    int nquad = N >> 2;
    float tri = 0.f;
    for (int quad = gw; quad < nquad; quad += 2 * nw) {
        int quadB = quad + nw;
        bool hasB = quadB < nquad;
        size_t base0 = (size_t)(quad * 4 + g) * DIM + seg * 4;
        size_t base1 = hasB ? ((size_t)(quadB * 4 + g) * DIM + seg * 4) : base0;
        nf4 a0[8], p0[8], q0[8], a1[8], p1[8], q1[8];
#pragma unroll
        for (int i = 0; i < 8; ++i) a0[i] = __builtin_nontemporal_load((const nf4*)(A + base0 + i * 64));
#pragma unroll
        for (int i = 0; i < 8; ++i) p0[i] = __builtin_nontemporal_load((const nf4*)(P + base0 + i * 64));
#pragma unroll
        for (int i = 0; i < 8; ++i) q0[i] = __builtin_nontemporal_load((const nf4*)(Q + base0 + i * 64));
#pragma unroll
        for (int i = 0; i < 8; ++i) a1[i] = __builtin_nontemporal_load((const nf4*)(A + base1 + i * 64));
#pragma unroll
        for (int i = 0; i < 8; ++i) p1[i] = __builtin_nontemporal_load((const nf4*)(P + base1 + i * 64));
#pragma unroll
        for (int i = 0; i < 8; ++i) q1[i] = __builtin_nontemporal_load((const nf4*)(Q + base1 + i * 64));
        {
            float sa = 0, sp = 0, sn = 0, dap = 0, dan = 0;
#pragma unroll
            for (int i = 0; i < 8; ++i) {
                sa  = fmaf(a0[i].x,a0[i].x, fmaf(a0[i].y,a0[i].y, fmaf(a0[i].z,a0[i].z, fmaf(a0[i].w,a0[i].w, sa))));
                sp  = fmaf(p0[i].x,p0[i].x, fmaf(p0[i].y,p0[i].y, fmaf(p0[i].z,p0[i].z, fmaf(p0[i].w,p0[i].w, sp))));
                sn  = fmaf(q0[i].x,q0[i].x, fmaf(q0[i].y,q0[i].y, fmaf(q0[i].z,q0[i].z, fmaf(q0[i].w,q0[i].w, sn))));
                dap = fmaf(a0[i].x,p0[i].x, fmaf(a0[i].y,p0[i].y, fmaf(a0[i].z,p0[i].z, fmaf(a0[i].w,p0[i].w, dap))));
                dan = fmaf(a0[i].x,q0[i].x, fmaf(a0[i].y,q0[i].y, fmaf(a0[i].z,q0[i].z, fmaf(a0[i].w,q0[i].w, dan))));
            }
#pragma unroll
            for (int o = 1; o < 16; o <<= 1) {
                sa  += __shfl_xor(sa,  o);
                sp  += __shfl_xor(sp,  o);
                sn  += __shfl_xor(sn,  o);
                dap += __shfl_xor(dap, o);
                dan += __shfl_xor(dan, o);
            }
            if (seg == 0) {
                float na = fmaxf(sqrtf(sa), EPSN);
                float np = fmaxf(sqrtf(sp), EPSN);
                float nn = fmaxf(sqrtf(sn), EPSN);
                tri += fmaxf((1.f - dap / (na * np)) - (1.f - dan / (na * nn)) + MARGIN, 0.f);
            }
        }
        if (hasB) {
            float sa = 0, sp = 0, sn = 0, dap = 0, dan = 0;
#pragma unroll
            for (int i = 0; i < 8; ++i) {
                sa  = fmaf(a1[i].x,a1[i].x, fmaf(a1[i].y,a1[i].y, fmaf(a1[i].z,a1[i].z, fmaf(a1[i].w,a1[i].w, sa))));
                sp  = fmaf(p1[i].x,p1[i].x, fmaf(p1[i].y,p1[i].y, fmaf(p1[i].z,p1[i].z, fmaf(p1[i].w,p1[i].w, sp))));
                sn  = fmaf(q1[i].x,q1[i].x, fmaf(q1[i].y,q1[i].y, fmaf(q1[i].z,q1[i].z, fmaf(q1[i].w,q1[i].w, sn))));
                dap = fmaf(a1[i].x,p1[i].x, fmaf(a1[i].y,p1[i].y, fmaf(a1[i].z,p1[i].z, fmaf(a1[i].w,p1[i].w, dap))));
                dan = fmaf(a1[i].x,q1[i].x, fmaf(a1[i].y,q1[i].y, fmaf(a1[i].z,q1[i].z, fmaf(a1[i].w,q1[i].w, dan))));
            }
#pragma unroll
            for (int o = 1; o < 16; o <<= 1) {
                sa  += __shfl_xor(sa,  o);
                sp  += __shfl_xor(sp,  o);
                sn  += __shfl_xor(sn,  o);
                dap += __shfl_xor(dap, o);
                dan += __shfl_xor(dan, o);
            }
            if (seg == 0) {
                float na = fmaxf(sqrtf(sa), EPSN);
                float np = fmaxf(sqrtf(sp), EPSN);
                float nn = fmaxf(sqrtf(sn), EPSN);
                tri += fmaxf((1.f - dap / (na * np)) - (1.f - dan / (na * nn)) + MARGIN, 0.f);
            }
        }
    }
    tri += __shfl_xor(tri, 16);
    tri += __shfl_xor(tri, 32);
    if (lane == 0) red[wid] = tri;
    __syncthreads();
    if (t == 0) atomicAdd(&scal[0], red[0] + red[1] + red[2] + red[3]);
}

// ---------------- Kernel 2: per-class sums (EXACT R10 form — no tail) ----------------
__global__ __launch_bounds__(256) void k_segsum(const float* __restrict__ E,
                                                const int* __restrict__ L,
                                                float* __restrict__ sums, int N) {
    __shared__ float acc[NCLS * 256];    // exactly 16 KB
    int t = threadIdx.x;
    int half = blockIdx.x & 1;
    int rg = blockIdx.x >> 1;
    int rpg = N >> 9;
    int r0 = rg * rpg;
    for (int i = t; i < NCLS * 256; i += 256) acc[i] = 0.f;
    __syncthreads();
    const float* Eh = E + half * 256 + t;
    for (int r = r0; r < r0 + rpg; r += 16) {
        int l[16];
        float v[16];
#pragma unroll
        for (int i = 0; i < 16; ++i) l[i] = L[r + i];
#pragma unroll
        for (int i = 0; i < 16; ++i) v[i] = Eh[(size_t)(r + i) * DIM];
#pragma unroll
        for (int i = 0; i < 16; ++i) acc[l[i] * 256 + t] += v[i];
    }
    __syncthreads();
#pragma unroll
    for (int c = 0; c < NCLS; ++c)
        atomicAdd(&sums[c * DIM + half * 256 + t], acc[c * 256 + t]);
}

// ---------------- Kernel 3 (tiny, 1 block): centroids, pair, cf, n_terms ----------------
__global__ __launch_bounds__(256) void k_centroid(const int* __restrict__ cpart,
                                                  const float* __restrict__ sums,
                                                  float* __restrict__ ncn_g,
                                                  float* __restrict__ pr_g,
                                                  float* __restrict__ cf_g,
                                                  float* __restrict__ ntv) {
    __shared__ float ncns[NCLS * NSTR];
    __shared__ float prs[NCLS * NCLS];
    __shared__ float cntl[NCLS];
    int t = threadIdx.x;
    if (t < NCLS) {
        int s = 0;
        for (int b = 0; b < 64; ++b) s += cpart[b * NCLS + t];
        cntl[t] = (float)s;
    }
    __syncthreads();
    {   // centroids: group c = t>>4 (16 threads each)
        int c = t >> 4, sI = t & 15;
        float inv = 1.f / fmaxf(cntl[c], 1.f);
        float4 v[8];
        float ssq = 0.f;
#pragma unroll
        for (int i = 0; i < 8; ++i) {
            v[i] = *(const float4*)(sums + c * DIM + sI * 32 + i * 4);
            v[i].x *= inv; v[i].y *= inv; v[i].z *= inv; v[i].w *= inv;
            ssq = fmaf(v[i].x, v[i].x, fmaf(v[i].y, v[i].y, fmaf(v[i].z, v[i].z, fmaf(v[i].w, v[i].w, ssq))));
        }
#pragma unroll
        for (int o = 1; o < 16; o <<= 1) ssq += __shfl_xor(ssq, o);
        float rs = 1.f / fmaxf(sqrtf(ssq), EPSN);
#pragma unroll
        for (int i = 0; i < 8; ++i) {
            float4 w = v[i];
            w.x *= rs; w.y *= rs; w.z *= rs; w.w *= rs;
            *(float4*)&ncns[c * NSTR + sI * 32 + i * 4] = w;
            *(float4*)(ncn_g + c * DIM + sI * 32 + i * 4) = w;
        }
    }
    __syncthreads();
    {   // fp32 pair matrix from padded LDS
        int i = t >> 4, j = t & 15;
        float dot = 0.f;
        for (int d = 0; d < DIM; d += 4) {
            float4 a = *(const float4*)&ncns[i * NSTR + d];
            float4 b = *(const float4*)&ncns[j * NSTR + d];
            dot = fmaf(a.x, b.x, fmaf(a.y, b.y, fmaf(a.z, b.z, fmaf(a.w, b.w, dot))));
        }
        float cd = 1.f - dot;
        float pf = (cd <= BETA && i != j && cntl[i] > 0.f && cntl[j] > 0.f) ? 1.f : 0.f;
        prs[t] = pf;
        pr_g[t] = pf;
    }
    __syncthreads();
    if (t < NCLS) {
        float s = 0.f;
#pragma unroll
        for (int k = 0; k < NCLS; ++k) s += prs[t * 16 + k];
        cf_g[t] = s;
        cntl[t] = cntl[t] * s;
    }
    __syncthreads();
    if (t == 0) {
        float nt = 0.f;
#pragma unroll
        for (int k = 0; k < NCLS; ++k) nt += cntl[k];
        ntv[0] = nt;
        ntv[1] = 1.f / fmaxf(nt, 1.f);
    }
}

// ---------------- Kernel 4: ATN main loop (R11 burst form) + last-block final ----------------
__global__ __launch_bounds__(256, 4) void k_atn(const float* __restrict__ E,
                                                const int* __restrict__ L,
                                                const float* __restrict__ ncn,
                                                const float* __restrict__ pr_g,
                                                const float* __restrict__ cf_g,
                                                const float* __restrict__ ntv,
                                                float* __restrict__ scal,
                                                unsigned* __restrict__ done,
                                                float* __restrict__ out,
                                                float invN, int N) {
    __shared__ float pr[NCLS * NCLS];
    __shared__ float cf[NCLS];
    __shared__ float red[8];
    int t = threadIdx.x, lane = t & 63, wid = t >> 6;
    pr[t] = pr_g[t];
    if (t < NCLS) cf[t] = cf_g[t];
    __syncthreads();

    int col = lane & 15;
    int kg = lane >> 4;
    short8 bfr[16];
#pragma unroll
    for (int s = 0; s < 16; ++s) {
        float4 q0 = *(const float4*)(ncn + col * DIM + s * 32 + kg * 8);
        float4 q1 = *(const float4*)(ncn + col * DIM + s * 32 + kg * 8 + 4);
        bfr[s] = pack8(q0, q1);
    }

    float inter = 0.f, intra = 0.f;
    int gw = blockIdx.x * 4 + wid, nw = gridDim.x * 4;
    int ntile = N >> 4;
    for (int tile = gw; tile < ntile; tile += nw) {
        int rowb = tile << 4;
        const float* ar = E + (size_t)(rowb + col) * DIM + kg * 8;
        f32x4 ac0 = {0,0,0,0}, ac1 = {0,0,0,0}, ac2 = {0,0,0,0}, ac3 = {0,0,0,0};
        float ss0 = 0.f, ss1 = 0.f, ss2 = 0.f, ss3 = 0.f;
#pragma unroll
        for (int sg = 0; sg < 4; ++sg) {
            float4 x[8];
#pragma unroll
            for (int k = 0; k < 8; ++k)
                x[k] = *(const float4*)(ar + sg * 128 + (k >> 1) * 32 + (k & 1) * 4);
            {
                float4 u = x[0], v = x[1];
                ss0 = fmaf(u.x,u.x, fmaf(u.y,u.y, fmaf(u.z,u.z, fmaf(u.w,u.w, ss0))));
                ss0 = fmaf(v.x,v.x, fmaf(v.y,v.y, fmaf(v.z,v.z, fmaf(v.w,v.w, ss0))));
                ac0 = __builtin_amdgcn_mfma_f32_16x16x32_bf16(pack8(u, v), bfr[sg * 4 + 0], ac0, 0, 0, 0);
            }
            {
                float4 u = x[2], v = x[3];
                ss1 = fmaf(u.x,u.x, fmaf(u.y,u.y, fmaf(u.z,u.z, fmaf(u.w,u.w, ss1))));
                ss1 = fmaf(v.x,v.x, fmaf(v.y,v.y, fmaf(v.z,v.z, fmaf(v.w,v.w, ss1))));
                ac1 = __builtin_amdgcn_mfma_f32_16x16x32_bf16(pack8(u, v), bfr[sg * 4 + 1], ac1, 0, 0, 0);
            }
            {
                float4 u = x[4], v = x[5];
                ss2 = fmaf(u.x,u.x, fmaf(u.y,u.y, fmaf(u.z,u.z, fmaf(u.w,u.w, ss2))));
                ss2 = fmaf(v.x,v.x, fmaf(v.y,v.y, fmaf(v.z,v.z, fmaf(v.w,v.w, ss2))));
                ac2 = __builtin_amdgcn_mfma_f32_16x16x32_bf16(pack8(u, v), bfr[sg * 4 + 2], ac2, 0, 0, 0);
            }
            {
                float4 u = x[6], v = x[7];
                ss3 = fmaf(u.x,u.x, fmaf(u.y,u.y, fmaf(u.z,u.z, fmaf(u.w,u.w, ss3))));
                ss3 = fmaf(v.x,v.x, fmaf(v.y,v.y, fmaf(v.z,v.z, fmaf(v.w,v.w, ss3))));
                ac3 = __builtin_amdgcn_mfma_f32_16x16x32_bf16(pack8(u, v), bfr[sg * 4 + 3], ac3, 0, 0, 0);
            }
        }
        f32x4 accv = (ac0 + ac1) + (ac2 + ac3);
        float ss = (ss0 + ss1) + (ss2 + ss3);
        ss += __shfl_xor(ss, 16);
        ss += __shfl_xor(ss, 32);
#pragma unroll
        for (int reg = 0; reg < 4; ++reg) {
            int row = kg * 4 + reg;
            float s2 = __shfl(ss, row);
            float rinv = 1.f / fmaxf(sqrtf(s2), EPSN);
            float d = 1.f - accv[reg] * rinv;
            int lab = L[rowb + row];
            inter += pr[lab * 16 + col] * fmaxf(BETA - d, 0.f);
            if (col == lab) intra += cf[lab] * fmaxf(d - ALPHA, 0.f);
        }
    }
#pragma unroll
    for (int o = 32; o > 0; o >>= 1) {
        inter += __shfl_xor(inter, o);
        intra += __shfl_xor(intra, o);
    }
    if (lane == 0) { red[wid] = intra; red[4 + wid] = inter; }
    __syncthreads();
    if (t == 0) {
        atomicAdd(&scal[1], red[0] + red[1] + red[2] + red[3]);
        atomicAdd(&scal[2], red[4] + red[5] + red[6] + red[7]);
        __threadfence();
        unsigned old = atomicAdd(done, 1u);
        if (old == gridDim.x - 1) {
            __threadfence();
            float tri  = atomicAdd(&scal[0], 0.f);
            float intr = atomicAdd(&scal[1], 0.f);
            float inte = atomicAdd(&scal[2], 0.f);
            float nt = ntv[0];
            float atnv = (nt > 0.f) ? (intr + inte) * ntv[1] : 0.f;
            out[0] = tri * invN + atnv;
        }
    }
}

extern "C" void kernel_launch(void* const* d_in, const int* in_sizes, int n_in,
                              void* d_out, int out_size, void* d_ws, size_t ws_size,
                              hipStream_t stream) {
    const float* A = (const float*)d_in[0];
    const float* P = (const float*)d_in[1];
    const float* Q = (const float*)d_in[2];
    const float* E = (const float*)d_in[3];
    const int*   L = (const int*)d_in[4];
    int N = in_sizes[0] / DIM;

    float*    wsf   = (float*)d_ws;
    float*    sums  = wsf;
    int*      cpart = (int*)(wsf + 8192);
    float*    scal  = wsf + 9216;
    unsigned* done  = (unsigned*)(wsf + 9224);
    float*    ncn   = wsf + 9232;
    float*    prg   = wsf + 17424;
    float*    cfg   = wsf + 17680;
    float*    ntv   = wsf + 17696;

    k_init     <<<64,   256, 0, stream>>>(L, wsf, cpart, N);
    k_triplet  <<<2048, 256, 0, stream>>>(A, P, Q, scal, N);
    k_segsum   <<<1024, 256, 0, stream>>>(E, L, sums, N);
    k_centroid <<<1,    256, 0, stream>>>(cpart, sums, ncn, prg, cfg, ntv);
    k_atn      <<<1024, 256, 0, stream>>>(E, L, ncn, prg, cfg, ntv, scal, done,
                                          (float*)d_out, 1.f / (float)N, N);
}

// Round 13
// 185.326 us; speedup vs baseline: 1.1640x; 1.0343x over previous
//
#include <hip/hip_runtime.h>

#define EPSN   1e-8f
#define MARGIN 0.2f
#define ALPHA  0.1f
#define BETA   1.05f
#define DIM    512
#define NCLS   16
#define NSTR   516   // padded LDS stride for centroid kernel

typedef __attribute__((ext_vector_type(8))) short short8;
typedef __attribute__((ext_vector_type(4))) float f32x4;
typedef __attribute__((ext_vector_type(4))) float nf4;

__device__ __forceinline__ unsigned short f2bf(float f) {
    unsigned u = __float_as_uint(f);
    return (unsigned short)((u + 0x7FFFu + ((u >> 16) & 1u)) >> 16);  // RNE
}
__device__ __forceinline__ short8 pack8(float4 x0, float4 x1) {
    short8 r;
    r[0] = (short)f2bf(x0.x); r[1] = (short)f2bf(x0.y);
    r[2] = (short)f2bf(x0.z); r[3] = (short)f2bf(x0.w);
    r[4] = (short)f2bf(x1.x); r[5] = (short)f2bf(x1.y);
    r[6] = (short)f2bf(x1.z); r[7] = (short)f2bf(x1.w);
    return r;
}

// ws layout (f32 words):
//     0: sums[8192]       8192: cpart i32[64][16]   9216: scal[8]   9224: done u32
//  9232: ncnh bf16[8192] (as 4096 u32)   13328: pr[256]   13584: cf[16]   13600: ntv[2]

// ---------------- Kernel 0: init = zero accumulators + label histogram partials ----------------
__global__ __launch_bounds__(256) void k_init(const int* __restrict__ L,
                                              float* __restrict__ wsw,
                                              int* __restrict__ cpart, int N) {
    __shared__ int hist[NCLS];
    int t = threadIdx.x, bid = blockIdx.x;
    int gid = bid * 256 + t;
    for (int i = gid; i < 8192; i += 64 * 256) wsw[i] = 0.f;
    if (gid < 16) wsw[9216 + gid] = 0.f;   // scal + done
    if (t < NCLS) hist[t] = 0;
    __syncthreads();
    int chunk = N >> 6;
    int base = bid * chunk;
    for (int i = t * 4; i < chunk; i += 1024) {
        int4 l4 = *(const int4*)(L + base + i);
        atomicAdd(&hist[l4.x], 1);
        atomicAdd(&hist[l4.y], 1);
        atomicAdd(&hist[l4.z], 1);
        atomicAdd(&hist[l4.w], 1);
    }
    __syncthreads();
    if (t < NCLS) cpart[bid * NCLS + t] = hist[t];
}

// ---------------- Kernel 1: triplet loss partial sum -> scal[0] ----------------
// R5-proven: nt loads, 2-deep pipeline, coalesced 256B chunks, 16-lane reduce.
__global__ __launch_bounds__(256) void k_triplet(const float* __restrict__ A,
                                                 const float* __restrict__ P,
                                                 const float* __restrict__ Q,
                                                 float* __restrict__ scal, int N) {
    __shared__ float red[4];
    int t = threadIdx.x, lane = t & 63, wid = t >> 6;
    int g = lane >> 4, seg = lane & 15;
    int gw = blockIdx.x * 4 + wid, nw = gridDim.x * 4;
    int nquad = N >> 2;
    float tri = 0.f;
    for (int quad = gw; quad < nquad; quad += 2 * nw) {
        int quadB = quad + nw;
        bool hasB = quadB < nquad;
        size_t base0 = (size_t)(quad * 4 + g) * DIM + seg * 4;
        size_t base1 = hasB ? ((size_t)(quadB * 4 + g) * DIM + seg * 4) : base0;
        nf4 a0[8], p0[8], q0[8], a1[8], p1[8], q1[8];
#pragma unroll
        for (int i = 0; i < 8; ++i) a0[i] = __builtin_nontemporal_load((const nf4*)(A + base0 + i * 64));
#pragma unroll
        for (int i = 0; i < 8; ++i) p0[i] = __builtin_nontemporal_load((const nf4*)(P + base0 + i * 64));
#pragma unroll
        for (int i = 0; i < 8; ++i) q0[i] = __builtin_nontemporal_load((const nf4*)(Q + base0 + i * 64));
#pragma unroll
        for (int i = 0; i < 8; ++i) a1[i] = __builtin_nontemporal_load((const nf4*)(A + base1 + i * 64));
#pragma unroll
        for (int i = 0; i < 8; ++i) p1[i] = __builtin_nontemporal_load((const nf4*)(P + base1 + i * 64));
#pragma unroll
        for (int i = 0; i < 8; ++i) q1[i] = __builtin_nontemporal_load((const nf4*)(Q + base1 + i * 64));
        {
            float sa = 0, sp = 0, sn = 0, dap = 0, dan = 0;
#pragma unroll
            for (int i = 0; i < 8; ++i) {
                sa  = fmaf(a0[i].x,a0[i].x, fmaf(a0[i].y,a0[i].y, fmaf(a0[i].z,a0[i].z, fmaf(a0[i].w,a0[i].w, sa))));
                sp  = fmaf(p0[i].x,p0[i].x, fmaf(p0[i].y,p0[i].y, fmaf(p0[i].z,p0[i].z, fmaf(p0[i].w,p0[i].w, sp))));
                sn  = fmaf(q0[i].x,q0[i].x, fmaf(q0[i].y,q0[i].y, fmaf(q0[i].z,q0[i].z, fmaf(q0[i].w,q0[i].w, sn))));
                dap = fmaf(a0[i].x,p0[i].x, fmaf(a0[i].y,p0[i].y, fmaf(a0[i].z,p0[i].z, fmaf(a0[i].w,p0[i].w, dap))));
                dan = fmaf(a0[i].x,q0[i].x, fmaf(a0[i].y,q0[i].y, fmaf(a0[i].z,q0[i].z, fmaf(a0[i].w,q0[i].w, dan))));
            }
#pragma unroll
            for (int o = 1; o < 16; o <<= 1) {
                sa  += __shfl_xor(sa,  o);
                sp  += __shfl_xor(sp,  o);
                sn  += __shfl_xor(sn,  o);
                dap += __shfl_xor(dap, o);
                dan += __shfl_xor(dan, o);
            }
            if (seg == 0) {
                float na = fmaxf(sqrtf(sa), EPSN);
                float np = fmaxf(sqrtf(sp), EPSN);
                float nn = fmaxf(sqrtf(sn), EPSN);
                tri += fmaxf((1.f - dap / (na * np)) - (1.f - dan / (na * nn)) + MARGIN, 0.f);
            }
        }
        if (hasB) {
            float sa = 0, sp = 0, sn = 0, dap = 0, dan = 0;
#pragma unroll
            for (int i = 0; i < 8; ++i) {
                sa  = fmaf(a1[i].x,a1[i].x, fmaf(a1[i].y,a1[i].y, fmaf(a1[i].z,a1[i].z, fmaf(a1[i].w,a1[i].w, sa))));
                sp  = fmaf(p1[i].x,p1[i].x, fmaf(p1[i].y,p1[i].y, fmaf(p1[i].z,p1[i].z, fmaf(p1[i].w,p1[i].w, sp))));
                sn  = fmaf(q1[i].x,q1[i].x, fmaf(q1[i].y,q1[i].y, fmaf(q1[i].z,q1[i].z, fmaf(q1[i].w,q1[i].w, sn))));
                dap = fmaf(a1[i].x,p1[i].x, fmaf(a1[i].y,p1[i].y, fmaf(a1[i].z,p1[i].z, fmaf(a1[i].w,p1[i].w, dap))));
                dan = fmaf(a1[i].x,q1[i].x, fmaf(a1[i].y,q1[i].y, fmaf(a1[i].z,q1[i].z, fmaf(a1[i].w,q1[i].w, dan))));
            }
#pragma unroll
            for (int o = 1; o < 16; o <<= 1) {
                sa  += __shfl_xor(sa,  o);
                sp  += __shfl_xor(sp,  o);
                sn  += __shfl_xor(sn,  o);
                dap += __shfl_xor(dap, o);
                dan += __shfl_xor(dan, o);
            }
            if (seg == 0) {
                float na = fmaxf(sqrtf(sa), EPSN);
                float np = fmaxf(sqrtf(sp), EPSN);
                float nn = fmaxf(sqrtf(sn), EPSN);
                tri += fmaxf((1.f - dap / (na * np)) - (1.f - dan / (na * nn)) + MARGIN, 0.f);
            }
        }
    }
    tri += __shfl_xor(tri, 16);
    tri += __shfl_xor(tri, 32);
    if (lane == 0) red[wid] = tri;
    __syncthreads();
    if (t == 0) atomicAdd(&scal[0], red[0] + red[1] + red[2] + red[3]);
}

// ---------------- Kernel 2: per-class sums (R10 form) ----------------
__global__ __launch_bounds__(256) void k_segsum(const float* __restrict__ E,
                                                const int* __restrict__ L,
                                                float* __restrict__ sums, int N) {
    __shared__ float acc[NCLS * 256];    // exactly 16 KB
    int t = threadIdx.x;
    int half = blockIdx.x & 1;
    int rg = blockIdx.x >> 1;
    int rpg = N >> 9;
    int r0 = rg * rpg;
    for (int i = t; i < NCLS * 256; i += 256) acc[i] = 0.f;
    __syncthreads();
    const float* Eh = E + half * 256 + t;
    for (int r = r0; r < r0 + rpg; r += 16) {
        int l[16];
        float v[16];
#pragma unroll
        for (int i = 0; i < 16; ++i) l[i] = L[r + i];
#pragma unroll
        for (int i = 0; i < 16; ++i) v[i] = Eh[(size_t)(r + i) * DIM];
#pragma unroll
        for (int i = 0; i < 16; ++i) acc[l[i] * 256 + t] += v[i];
    }
    __syncthreads();
#pragma unroll
    for (int c = 0; c < NCLS; ++c)
        atomicAdd(&sums[c * DIM + half * 256 + t], acc[c * 256 + t]);
}

// ---------------- Kernel 3 (tiny, 1 block): centroids, pair, cf, n_terms, bf16 centroids ----------------
__global__ __launch_bounds__(256) void k_centroid(const int* __restrict__ cpart,
                                                  const float* __restrict__ sums,
                                                  unsigned short* __restrict__ ncnh,
                                                  float* __restrict__ pr_g,
                                                  float* __restrict__ cf_g,
                                                  float* __restrict__ ntv) {
    __shared__ float ncns[NCLS * NSTR];
    __shared__ float prs[NCLS * NCLS];
    __shared__ float cntl[NCLS];
    int t = threadIdx.x;
    if (t < NCLS) {
        int s = 0;
        for (int b = 0; b < 64; ++b) s += cpart[b * NCLS + t];
        cntl[t] = (float)s;
    }
    __syncthreads();
    {   // centroids: group c = t>>4 (16 threads each)
        int c = t >> 4, sI = t & 15;
        float inv = 1.f / fmaxf(cntl[c], 1.f);
        float4 v[8];
        float ssq = 0.f;
#pragma unroll
        for (int i = 0; i < 8; ++i) {
            v[i] = *(const float4*)(sums + c * DIM + sI * 32 + i * 4);
            v[i].x *= inv; v[i].y *= inv; v[i].z *= inv; v[i].w *= inv;
            ssq = fmaf(v[i].x, v[i].x, fmaf(v[i].y, v[i].y, fmaf(v[i].z, v[i].z, fmaf(v[i].w, v[i].w, ssq))));
        }
#pragma unroll
        for (int o = 1; o < 16; o <<= 1) ssq += __shfl_xor(ssq, o);
        float rs = 1.f / fmaxf(sqrtf(ssq), EPSN);
#pragma unroll
        for (int i = 0; i < 8; ++i) {
            float4 w = v[i];
            w.x *= rs; w.y *= rs; w.z *= rs; w.w *= rs;
            *(float4*)&ncns[c * NSTR + sI * 32 + i * 4] = w;
            ushort4 h;
            h.x = f2bf(w.x); h.y = f2bf(w.y); h.z = f2bf(w.z); h.w = f2bf(w.w);
            *(ushort4*)(ncnh + c * DIM + sI * 32 + i * 4) = h;
        }
    }
    __syncthreads();
    {   // fp32 pair matrix from padded LDS
        int i = t >> 4, j = t & 15;
        float dot = 0.f;
        for (int d = 0; d < DIM; d += 4) {
            float4 a = *(const float4*)&ncns[i * NSTR + d];
            float4 b = *(const float4*)&ncns[j * NSTR + d];
            dot = fmaf(a.x, b.x, fmaf(a.y, b.y, fmaf(a.z, b.z, fmaf(a.w, b.w, dot))));
        }
        float cd = 1.f - dot;
        float pf = (cd <= BETA && i != j && cntl[i] > 0.f && cntl[j] > 0.f) ? 1.f : 0.f;
        prs[t] = pf;
        pr_g[t] = pf;
    }
    __syncthreads();
    if (t < NCLS) {
        float s = 0.f;
#pragma unroll
        for (int k = 0; k < NCLS; ++k) s += prs[t * 16 + k];
        cf_g[t] = s;
        cntl[t] = cntl[t] * s;
    }
    __syncthreads();
    if (t == 0) {
        float nt = 0.f;
#pragma unroll
        for (int k = 0; k < NCLS; ++k) nt += cntl[k];
        ntv[0] = nt;
        ntv[1] = 1.f / fmaxf(nt, 1.f);
    }
}

// ---------------- Kernel 4: ATN — B-fragments in LDS (frees 64 VGPRs), last-block final ----------------
// LDS B layout [s][kg][col][8 bf16]: per 16-lane quarter each lane reads a
// distinct 16B slot -> quarter-wise conflict-free ds_read_b128.
__global__ __launch_bounds__(256) void k_atn(const float* __restrict__ E,
                                             const int* __restrict__ L,
                                             const unsigned short* __restrict__ ncnh,
                                             const float* __restrict__ pr_g,
                                             const float* __restrict__ cf_g,
                                             const float* __restrict__ ntv,
                                             float* __restrict__ scal,
                                             unsigned* __restrict__ done,
                                             float* __restrict__ out,
                                             float invN, int N) {
    __shared__ short bsh[16 * 4 * 16 * 8];   // 16 KB: [s][kg][col][8]
    __shared__ float pr[NCLS * NCLS];
    __shared__ float cf[NCLS];
    __shared__ float red[8];
    int t = threadIdx.x, lane = t & 63, wid = t >> 6;
    pr[t] = pr_g[t];
    if (t < NCLS) cf[t] = cf_g[t];
    {   // stage bf16 centroids into fragment-ordered LDS
        int ccol = t & 15, ckg = (t >> 4) & 3, sb = t >> 6;   // sb 0..3
#pragma unroll
        for (int i = 0; i < 4; ++i) {
            int s = sb * 4 + i;
            uint4 w = *(const uint4*)(ncnh + ccol * DIM + s * 32 + ckg * 8);
            *(uint4*)&bsh[((s * 4 + ckg) * 16 + ccol) * 8] = w;
        }
    }
    __syncthreads();

    int col = lane & 15;
    int kg = lane >> 4;
    const short* bbase = &bsh[(kg * 16 + col) * 8];   // step s at offset s*512 shorts

    float inter = 0.f, intra = 0.f;
    int gw = blockIdx.x * 4 + wid, nw = gridDim.x * 4;
    int ntile = N >> 4;
    for (int tile = gw; tile < ntile; tile += nw) {
        int rowb = tile << 4;
        int lval = L[rowb + col];                      // 16 labels held across quarter
        const float* ar = E + (size_t)(rowb + col) * DIM + kg * 8;
        f32x4 ac0 = {0,0,0,0}, ac1 = {0,0,0,0}, ac2 = {0,0,0,0}, ac3 = {0,0,0,0};
        float ss0 = 0.f, ss1 = 0.f, ss2 = 0.f, ss3 = 0.f;
#pragma unroll
        for (int sg = 0; sg < 4; ++sg) {
            float4 x[8];
#pragma unroll
            for (int k = 0; k < 8; ++k)
                x[k] = *(const float4*)(ar + sg * 128 + (k >> 1) * 32 + (k & 1) * 4);
            {
                float4 u = x[0], v = x[1];
                short8 bf = *(const short8*)(bbase + (sg * 4 + 0) * 512);
                ss0 = fmaf(u.x,u.x, fmaf(u.y,u.y, fmaf(u.z,u.z, fmaf(u.w,u.w, ss0))));
                ss0 = fmaf(v.x,v.x, fmaf(v.y,v.y, fmaf(v.z,v.z, fmaf(v.w,v.w, ss0))));
                ac0 = __builtin_amdgcn_mfma_f32_16x16x32_bf16(pack8(u, v), bf, ac0, 0, 0, 0);
            }
            {
                float4 u = x[2], v = x[3];
                short8 bf = *(const short8*)(bbase + (sg * 4 + 1) * 512);
                ss1 = fmaf(u.x,u.x, fmaf(u.y,u.y, fmaf(u.z,u.z, fmaf(u.w,u.w, ss1))));
                ss1 = fmaf(v.x,v.x, fmaf(v.y,v.y, fmaf(v.z,v.z, fmaf(v.w,v.w, ss1))));
                ac1 = __builtin_amdgcn_mfma_f32_16x16x32_bf16(pack8(u, v), bf, ac1, 0, 0, 0);
            }
            {
                float4 u = x[4], v = x[5];
                short8 bf = *(const short8*)(bbase + (sg * 4 + 2) * 512);
                ss2 = fmaf(u.x,u.x, fmaf(u.y,u.y, fmaf(u.z,u.z, fmaf(u.w,u.w, ss2))));
                ss2 = fmaf(v.x,v.x, fmaf(v.y,v.y, fmaf(v.z,v.z, fmaf(v.w,v.w, ss2))));
                ac2 = __builtin_amdgcn_mfma_f32_16x16x32_bf16(pack8(u, v), bf, ac2, 0, 0, 0);
            }
            {
                float4 u = x[6], v = x[7];
                short8 bf = *(const short8*)(bbase + (sg * 4 + 3) * 512);
                ss3 = fmaf(u.x,u.x, fmaf(u.y,u.y, fmaf(u.z,u.z, fmaf(u.w,u.w, ss3))));
                ss3 = fmaf(v.x,v.x, fmaf(v.y,v.y, fmaf(v.z,v.z, fmaf(v.w,v.w, ss3))));
                ac3 = __builtin_amdgcn_mfma_f32_16x16x32_bf16(pack8(u, v), bf, ac3, 0, 0, 0);
            }
        }
        f32x4 accv = (ac0 + ac1) + (ac2 + ac3);
        float ss = (ss0 + ss1) + (ss2 + ss3);
        ss += __shfl_xor(ss, 16);
        ss += __shfl_xor(ss, 32);
#pragma unroll
        for (int reg = 0; reg < 4; ++reg) {
            int row = kg * 4 + reg;
            float s2 = __shfl(ss, row);
            int lab = __shfl(lval, (lane & 48) | row);   // broadcast within quarter? no: label of row
            lab = __shfl(lval, row);                      // lval holder lane == row index (col==row)
            float rinv = 1.f / fmaxf(sqrtf(s2), EPSN);
            float d = 1.f - accv[reg] * rinv;
            inter += pr[lab * 16 + col] * fmaxf(BETA - d, 0.f);
            if (col == lab) intra += cf[lab] * fmaxf(d - ALPHA, 0.f);
        }
    }
#pragma unroll
    for (int o = 32; o > 0; o >>= 1) {
        inter += __shfl_xor(inter, o);
        intra += __shfl_xor(intra, o);
    }
    if (lane == 0) { red[wid] = intra; red[4 + wid] = inter; }
    __syncthreads();
    if (t == 0) {
        atomicAdd(&scal[1], red[0] + red[1] + red[2] + red[3]);
        atomicAdd(&scal[2], red[4] + red[5] + red[6] + red[7]);
        __threadfence();
        unsigned old = atomicAdd(done, 1u);
        if (old == gridDim.x - 1) {
            __threadfence();
            float tri  = atomicAdd(&scal[0], 0.f);
            float intr = atomicAdd(&scal[1], 0.f);
            float inte = atomicAdd(&scal[2], 0.f);
            float nt = ntv[0];
            float atnv = (nt > 0.f) ? (intr + inte) * ntv[1] : 0.f;
            out[0] = tri * invN + atnv;
        }
    }
}

extern "C" void kernel_launch(void* const* d_in, const int* in_sizes, int n_in,
                              void* d_out, int out_size, void* d_ws, size_t ws_size,
                              hipStream_t stream) {
    const float* A = (const float*)d_in[0];
    const float* P = (const float*)d_in[1];
    const float* Q = (const float*)d_in[2];
    const float* E = (const float*)d_in[3];
    const int*   L = (const int*)d_in[4];
    int N = in_sizes[0] / DIM;

    float*          wsf   = (float*)d_ws;
    float*          sums  = wsf;
    int*            cpart = (int*)(wsf + 8192);
    float*          scal  = wsf + 9216;
    unsigned*       done  = (unsigned*)(wsf + 9224);
    unsigned short* ncnh  = (unsigned short*)(wsf + 9232);   // 8192 bf16 = 16 KB
    float*          prg   = wsf + 13328;
    float*          cfg   = wsf + 13584;
    float*          ntv   = wsf + 13600;

    k_init     <<<64,   256, 0, stream>>>(L, wsf, cpart, N);
    k_triplet  <<<2048, 256, 0, stream>>>(A, P, Q, scal, N);
    k_segsum   <<<1024, 256, 0, stream>>>(E, L, sums, N);
    k_centroid <<<1,    256, 0, stream>>>(cpart, sums, ncnh, prg, cfg, ntv);
    k_atn      <<<1024, 256, 0, stream>>>(E, L, ncnh, prg, cfg, ntv, scal, done,
                                          (float*)d_out, 1.f / (float)N, N);
}

// Round 14
// 140.852 us; speedup vs baseline: 1.5316x; 1.3158x over previous
//
#include <hip/hip_runtime.h>

#define EPSN   1e-8f
#define MARGIN 0.2f
#define ALPHA  0.1f
#define BETA   1.05f
#define DIM    512
#define NCLS   16
#define NSTR   516

typedef __attribute__((ext_vector_type(8))) short short8;
typedef __attribute__((ext_vector_type(4))) float f32x4;
typedef __attribute__((ext_vector_type(4))) float nf4;

__device__ __forceinline__ unsigned short f2bf(float f) {
    unsigned u = __float_as_uint(f);
    return (unsigned short)((u + 0x7FFFu + ((u >> 16) & 1u)) >> 16);  // RNE
}
__device__ __forceinline__ short8 pack8(float4 x0, float4 x1) {
    short8 r;
    r[0] = (short)f2bf(x0.x); r[1] = (short)f2bf(x0.y);
    r[2] = (short)f2bf(x0.z); r[3] = (short)f2bf(x0.w);
    r[4] = (short)f2bf(x1.x); r[5] = (short)f2bf(x1.y);
    r[6] = (short)f2bf(x1.z); r[7] = (short)f2bf(x1.w);
    return r;
}

// ws layout (f32 words):
//     0: sums[8192]          8192: cpart i32[64][16]
//  9216: ncnh bf16[8192] (4096 words)    13312: pr[256]   13568: cf[16]   13584: ntv[2]
// 13600: tripart[2048]      15648: atnpart[1024]  (intra [0..512), inter [512..1024))

// ---------------- Kernel 0: init = zero sums + label histogram partials ----------------
__global__ __launch_bounds__(256) void k_init(const int* __restrict__ L,
                                              float* __restrict__ wsw,
                                              int* __restrict__ cpart, int N) {
    __shared__ int hist[NCLS];
    int t = threadIdx.x, bid = blockIdx.x;
    int gid = bid * 256 + t;
    for (int i = gid; i < 8192; i += 64 * 256) wsw[i] = 0.f;
    if (t < NCLS) hist[t] = 0;
    __syncthreads();
    int chunk = N >> 6;
    int base = bid * chunk;
    for (int i = t * 4; i < chunk; i += 1024) {
        int4 l4 = *(const int4*)(L + base + i);
        atomicAdd(&hist[l4.x], 1);
        atomicAdd(&hist[l4.y], 1);
        atomicAdd(&hist[l4.z], 1);
        atomicAdd(&hist[l4.w], 1);
    }
    __syncthreads();
    if (t < NCLS) cpart[bid * NCLS + t] = hist[t];
}

// ---------------- Kernel 1: triplet -> per-block partial (NO atomics) ----------------
__global__ __launch_bounds__(256) void k_triplet(const float* __restrict__ A,
                                                 const float* __restrict__ P,
                                                 const float* __restrict__ Q,
                                                 float* __restrict__ tripart, int N) {
    __shared__ float red[4];
    int t = threadIdx.x, lane = t & 63, wid = t >> 6;
    int g = lane >> 4, seg = lane & 15;
    int gw = blockIdx.x * 4 + wid, nw = gridDim.x * 4;
    int nquad = N >> 2;
    float tri = 0.f;
    for (int quad = gw; quad < nquad; quad += 2 * nw) {
        int quadB = quad + nw;
        bool hasB = quadB < nquad;
        size_t base0 = (size_t)(quad * 4 + g) * DIM + seg * 4;
        size_t base1 = hasB ? ((size_t)(quadB * 4 + g) * DIM + seg * 4) : base0;
        nf4 a0[8], p0[8], q0[8], a1[8], p1[8], q1[8];
#pragma unroll
        for (int i = 0; i < 8; ++i) a0[i] = __builtin_nontemporal_load((const nf4*)(A + base0 + i * 64));
#pragma unroll
        for (int i = 0; i < 8; ++i) p0[i] = __builtin_nontemporal_load((const nf4*)(P + base0 + i * 64));
#pragma unroll
        for (int i = 0; i < 8; ++i) q0[i] = __builtin_nontemporal_load((const nf4*)(Q + base0 + i * 64));
#pragma unroll
        for (int i = 0; i < 8; ++i) a1[i] = __builtin_nontemporal_load((const nf4*)(A + base1 + i * 64));
#pragma unroll
        for (int i = 0; i < 8; ++i) p1[i] = __builtin_nontemporal_load((const nf4*)(P + base1 + i * 64));
#pragma unroll
        for (int i = 0; i < 8; ++i) q1[i] = __builtin_nontemporal_load((const nf4*)(Q + base1 + i * 64));
        {
            float sa = 0, sp = 0, sn = 0, dap = 0, dan = 0;
#pragma unroll
            for (int i = 0; i < 8; ++i) {
                sa  = fmaf(a0[i].x,a0[i].x, fmaf(a0[i].y,a0[i].y, fmaf(a0[i].z,a0[i].z, fmaf(a0[i].w,a0[i].w, sa))));
                sp  = fmaf(p0[i].x,p0[i].x, fmaf(p0[i].y,p0[i].y, fmaf(p0[i].z,p0[i].z, fmaf(p0[i].w,p0[i].w, sp))));
                sn  = fmaf(q0[i].x,q0[i].x, fmaf(q0[i].y,q0[i].y, fmaf(q0[i].z,q0[i].z, fmaf(q0[i].w,q0[i].w, sn))));
                dap = fmaf(a0[i].x,p0[i].x, fmaf(a0[i].y,p0[i].y, fmaf(a0[i].z,p0[i].z, fmaf(a0[i].w,p0[i].w, dap))));
                dan = fmaf(a0[i].x,q0[i].x, fmaf(a0[i].y,q0[i].y, fmaf(a0[i].z,q0[i].z, fmaf(a0[i].w,q0[i].w, dan))));
            }
#pragma unroll
            for (int o = 1; o < 16; o <<= 1) {
                sa  += __shfl_xor(sa,  o);
                sp  += __shfl_xor(sp,  o);
                sn  += __shfl_xor(sn,  o);
                dap += __shfl_xor(dap, o);
                dan += __shfl_xor(dan, o);
            }
            if (seg == 0) {
                float na = fmaxf(sqrtf(sa), EPSN);
                float np = fmaxf(sqrtf(sp), EPSN);
                float nn = fmaxf(sqrtf(sn), EPSN);
                tri += fmaxf((1.f - dap / (na * np)) - (1.f - dan / (na * nn)) + MARGIN, 0.f);
            }
        }
        if (hasB) {
            float sa = 0, sp = 0, sn = 0, dap = 0, dan = 0;
#pragma unroll
            for (int i = 0; i < 8; ++i) {
                sa  = fmaf(a1[i].x,a1[i].x, fmaf(a1[i].y,a1[i].y, fmaf(a1[i].z,a1[i].z, fmaf(a1[i].w,a1[i].w, sa))));
                sp  = fmaf(p1[i].x,p1[i].x, fmaf(p1[i].y,p1[i].y, fmaf(p1[i].z,p1[i].z, fmaf(p1[i].w,p1[i].w, sp))));
                sn  = fmaf(q1[i].x,q1[i].x, fmaf(q1[i].y,q1[i].y, fmaf(q1[i].z,q1[i].z, fmaf(q1[i].w,q1[i].w, sn))));
                dap = fmaf(a1[i].x,p1[i].x, fmaf(a1[i].y,p1[i].y, fmaf(a1[i].z,p1[i].z, fmaf(a1[i].w,p1[i].w, dap))));
                dan = fmaf(a1[i].x,q1[i].x, fmaf(a1[i].y,q1[i].y, fmaf(a1[i].z,q1[i].z, fmaf(a1[i].w,q1[i].w, dan))));
            }
#pragma unroll
            for (int o = 1; o < 16; o <<= 1) {
                sa  += __shfl_xor(sa,  o);
                sp  += __shfl_xor(sp,  o);
                sn  += __shfl_xor(sn,  o);
                dap += __shfl_xor(dap, o);
                dan += __shfl_xor(dan, o);
            }
            if (seg == 0) {
                float na = fmaxf(sqrtf(sa), EPSN);
                float np = fmaxf(sqrtf(sp), EPSN);
                float nn = fmaxf(sqrtf(sn), EPSN);
                tri += fmaxf((1.f - dap / (na * np)) - (1.f - dan / (na * nn)) + MARGIN, 0.f);
            }
        }
    }
    tri += __shfl_xor(tri, 16);
    tri += __shfl_xor(tri, 32);
    if (lane == 0) red[wid] = tri;
    __syncthreads();
    if (t == 0) tripart[blockIdx.x] = red[0] + red[1] + red[2] + red[3];
}

// ---------------- Kernel 2: per-class sums (R10 form, distinct-address atomics) ----------------
__global__ __launch_bounds__(256) void k_segsum(const float* __restrict__ E,
                                                const int* __restrict__ L,
                                                float* __restrict__ sums, int N) {
    __shared__ float acc[NCLS * 256];    // exactly 16 KB
    int t = threadIdx.x;
    int half = blockIdx.x & 1;
    int rg = blockIdx.x >> 1;
    int rpg = N >> 9;
    int r0 = rg * rpg;
    for (int i = t; i < NCLS * 256; i += 256) acc[i] = 0.f;
    __syncthreads();
    const float* Eh = E + half * 256 + t;
    for (int r = r0; r < r0 + rpg; r += 16) {
        int l[16];
        float v[16];
#pragma unroll
        for (int i = 0; i < 16; ++i) l[i] = L[r + i];
#pragma unroll
        for (int i = 0; i < 16; ++i) v[i] = Eh[(size_t)(r + i) * DIM];
#pragma unroll
        for (int i = 0; i < 16; ++i) acc[l[i] * 256 + t] += v[i];
    }
    __syncthreads();
#pragma unroll
    for (int c = 0; c < NCLS; ++c)
        atomicAdd(&sums[c * DIM + half * 256 + t], acc[c * 256 + t]);
}

// ---------------- Kernel 3 (1 block): centroids, pair, cf, n_terms, bf16 centroids ----------------
__global__ __launch_bounds__(256) void k_centroid(const int* __restrict__ cpart,
                                                  const float* __restrict__ sums,
                                                  unsigned short* __restrict__ ncnh,
                                                  float* __restrict__ pr_g,
                                                  float* __restrict__ cf_g,
                                                  float* __restrict__ ntv) {
    __shared__ float ncns[NCLS * NSTR];
    __shared__ float prs[NCLS * NCLS];
    __shared__ float cntl[NCLS];
    int t = threadIdx.x;
    if (t < NCLS) {
        int s = 0;
        for (int b = 0; b < 64; ++b) s += cpart[b * NCLS + t];
        cntl[t] = (float)s;
    }
    __syncthreads();
    {
        int c = t >> 4, sI = t & 15;
        float inv = 1.f / fmaxf(cntl[c], 1.f);
        float4 v[8];
        float ssq = 0.f;
#pragma unroll
        for (int i = 0; i < 8; ++i) {
            v[i] = *(const float4*)(sums + c * DIM + sI * 32 + i * 4);
            v[i].x *= inv; v[i].y *= inv; v[i].z *= inv; v[i].w *= inv;
            ssq = fmaf(v[i].x, v[i].x, fmaf(v[i].y, v[i].y, fmaf(v[i].z, v[i].z, fmaf(v[i].w, v[i].w, ssq))));
        }
#pragma unroll
        for (int o = 1; o < 16; o <<= 1) ssq += __shfl_xor(ssq, o);
        float rs = 1.f / fmaxf(sqrtf(ssq), EPSN);
#pragma unroll
        for (int i = 0; i < 8; ++i) {
            float4 w = v[i];
            w.x *= rs; w.y *= rs; w.z *= rs; w.w *= rs;
            *(float4*)&ncns[c * NSTR + sI * 32 + i * 4] = w;
            ushort4 h;
            h.x = f2bf(w.x); h.y = f2bf(w.y); h.z = f2bf(w.z); h.w = f2bf(w.w);
            *(ushort4*)(ncnh + c * DIM + sI * 32 + i * 4) = h;
        }
    }
    __syncthreads();
    {
        int i = t >> 4, j = t & 15;
        float dot = 0.f;
        for (int d = 0; d < DIM; d += 4) {
            float4 a = *(const float4*)&ncns[i * NSTR + d];
            float4 b = *(const float4*)&ncns[j * NSTR + d];
            dot = fmaf(a.x, b.x, fmaf(a.y, b.y, fmaf(a.z, b.z, fmaf(a.w, b.w, dot))));
        }
        float cd = 1.f - dot;
        float pf = (cd <= BETA && i != j && cntl[i] > 0.f && cntl[j] > 0.f) ? 1.f : 0.f;
        prs[t] = pf;
        pr_g[t] = pf;
    }
    __syncthreads();
    if (t < NCLS) {
        float s = 0.f;
#pragma unroll
        for (int k = 0; k < NCLS; ++k) s += prs[t * 16 + k];
        cf_g[t] = s;
        cntl[t] = cntl[t] * s;
    }
    __syncthreads();
    if (t == 0) {
        float nt = 0.f;
#pragma unroll
        for (int k = 0; k < NCLS; ++k) nt += cntl[k];
        ntv[0] = nt;
        ntv[1] = 1.f / fmaxf(nt, 1.f);
    }
}

// ---------------- Kernel 4: ATN — per-block partials, NO atomics/fence/done ----------------
__global__ __launch_bounds__(256) void k_atn(const float* __restrict__ E,
                                             const int* __restrict__ L,
                                             const unsigned short* __restrict__ ncnh,
                                             const float* __restrict__ pr_g,
                                             const float* __restrict__ cf_g,
                                             float* __restrict__ atnpart,
                                             int nblk, int N) {
    __shared__ short bsh[16 * 4 * 16 * 8];   // 16 KB: [s][kg][col][8]
    __shared__ float pr[NCLS * NCLS];
    __shared__ float cf[NCLS];
    __shared__ float red[8];
    int t = threadIdx.x, lane = t & 63, wid = t >> 6;
    pr[t] = pr_g[t];
    if (t < NCLS) cf[t] = cf_g[t];
    {
        int ccol = t & 15, ckg = (t >> 4) & 3, sb = t >> 6;
#pragma unroll
        for (int i = 0; i < 4; ++i) {
            int s = sb * 4 + i;
            uint4 w = *(const uint4*)(ncnh + ccol * DIM + s * 32 + ckg * 8);
            *(uint4*)&bsh[((s * 4 + ckg) * 16 + ccol) * 8] = w;
        }
    }
    __syncthreads();

    int col = lane & 15;
    int kg = lane >> 4;
    const short* bbase = &bsh[(kg * 16 + col) * 8];

    float inter = 0.f, intra = 0.f;
    int gw = blockIdx.x * 4 + wid, nw = gridDim.x * 4;
    int ntile = N >> 4;
    for (int tile = gw; tile < ntile; tile += nw) {
        int rowb = tile << 4;
        int lval = L[rowb + col];
        const float* ar = E + (size_t)(rowb + col) * DIM + kg * 8;
        f32x4 ac0 = {0,0,0,0}, ac1 = {0,0,0,0}, ac2 = {0,0,0,0}, ac3 = {0,0,0,0};
        float ss0 = 0.f, ss1 = 0.f, ss2 = 0.f, ss3 = 0.f;
#pragma unroll
        for (int sg = 0; sg < 4; ++sg) {
            float4 x[8];
#pragma unroll
            for (int k = 0; k < 8; ++k)
                x[k] = *(const float4*)(ar + sg * 128 + (k >> 1) * 32 + (k & 1) * 4);
            {
                float4 u = x[0], v = x[1];
                short8 bf = *(const short8*)(bbase + (sg * 4 + 0) * 512);
                ss0 = fmaf(u.x,u.x, fmaf(u.y,u.y, fmaf(u.z,u.z, fmaf(u.w,u.w, ss0))));
                ss0 = fmaf(v.x,v.x, fmaf(v.y,v.y, fmaf(v.z,v.z, fmaf(v.w,v.w, ss0))));
                ac0 = __builtin_amdgcn_mfma_f32_16x16x32_bf16(pack8(u, v), bf, ac0, 0, 0, 0);
            }
            {
                float4 u = x[2], v = x[3];
                short8 bf = *(const short8*)(bbase + (sg * 4 + 1) * 512);
                ss1 = fmaf(u.x,u.x, fmaf(u.y,u.y, fmaf(u.z,u.z, fmaf(u.w,u.w, ss1))));
                ss1 = fmaf(v.x,v.x, fmaf(v.y,v.y, fmaf(v.z,v.z, fmaf(v.w,v.w, ss1))));
                ac1 = __builtin_amdgcn_mfma_f32_16x16x32_bf16(pack8(u, v), bf, ac1, 0, 0, 0);
            }
            {
                float4 u = x[4], v = x[5];
                short8 bf = *(const short8*)(bbase + (sg * 4 + 2) * 512);
                ss2 = fmaf(u.x,u.x, fmaf(u.y,u.y, fmaf(u.z,u.z, fmaf(u.w,u.w, ss2))));
                ss2 = fmaf(v.x,v.x, fmaf(v.y,v.y, fmaf(v.z,v.z, fmaf(v.w,v.w, ss2))));
                ac2 = __builtin_amdgcn_mfma_f32_16x16x32_bf16(pack8(u, v), bf, ac2, 0, 0, 0);
            }
            {
                float4 u = x[6], v = x[7];
                short8 bf = *(const short8*)(bbase + (sg * 4 + 3) * 512);
                ss3 = fmaf(u.x,u.x, fmaf(u.y,u.y, fmaf(u.z,u.z, fmaf(u.w,u.w, ss3))));
                ss3 = fmaf(v.x,v.x, fmaf(v.y,v.y, fmaf(v.z,v.z, fmaf(v.w,v.w, ss3))));
                ac3 = __builtin_amdgcn_mfma_f32_16x16x32_bf16(pack8(u, v), bf, ac3, 0, 0, 0);
            }
        }
        f32x4 accv = (ac0 + ac1) + (ac2 + ac3);
        float ss = (ss0 + ss1) + (ss2 + ss3);
        ss += __shfl_xor(ss, 16);
        ss += __shfl_xor(ss, 32);
#pragma unroll
        for (int reg = 0; reg < 4; ++reg) {
            int row = kg * 4 + reg;
            float s2 = __shfl(ss, row);
            int lab = __shfl(lval, row);
            float rinv = 1.f / fmaxf(sqrtf(s2), EPSN);
            float d = 1.f - accv[reg] * rinv;
            inter += pr[lab * 16 + col] * fmaxf(BETA - d, 0.f);
            if (col == lab) intra += cf[lab] * fmaxf(d - ALPHA, 0.f);
        }
    }
#pragma unroll
    for (int o = 32; o > 0; o >>= 1) {
        inter += __shfl_xor(inter, o);
        intra += __shfl_xor(intra, o);
    }
    if (lane == 0) { red[wid] = intra; red[4 + wid] = inter; }
    __syncthreads();
    if (t == 0) {
        atnpart[blockIdx.x]        = red[0] + red[1] + red[2] + red[3];
        atnpart[nblk + blockIdx.x] = red[4] + red[5] + red[6] + red[7];
    }
}

// ---------------- Kernel 5 (1 block): final reduction ----------------
__global__ __launch_bounds__(256) void k_final(const float* __restrict__ tripart,
                                               const float* __restrict__ atnpart,
                                               const float* __restrict__ ntv,
                                               float* __restrict__ out,
                                               float invN, int ntri, int natn) {
    __shared__ float r[12];
    int t = threadIdx.x, lane = t & 63, wid = t >> 6;
    float s_tri = 0.f, s_in = 0.f, s_ie = 0.f;
    for (int i = t; i < ntri; i += 256) s_tri += tripart[i];
    for (int i = t; i < natn; i += 256) { s_in += atnpart[i]; s_ie += atnpart[natn + i]; }
#pragma unroll
    for (int o = 1; o < 64; o <<= 1) {
        s_tri += __shfl_xor(s_tri, o);
        s_in  += __shfl_xor(s_in,  o);
        s_ie  += __shfl_xor(s_ie,  o);
    }
    if (lane == 0) { r[wid] = s_tri; r[4 + wid] = s_in; r[8 + wid] = s_ie; }
    __syncthreads();
    if (t == 0) {
        float tri = r[0] + r[1] + r[2] + r[3];
        float in2 = r[4] + r[5] + r[6] + r[7];
        float ie2 = r[8] + r[9] + r[10] + r[11];
        float nt = ntv[0];
        float atnv = (nt > 0.f) ? (in2 + ie2) * ntv[1] : 0.f;
        out[0] = tri * invN + atnv;
    }
}

extern "C" void kernel_launch(void* const* d_in, const int* in_sizes, int n_in,
                              void* d_out, int out_size, void* d_ws, size_t ws_size,
                              hipStream_t stream) {
    const float* A = (const float*)d_in[0];
    const float* P = (const float*)d_in[1];
    const float* Q = (const float*)d_in[2];
    const float* E = (const float*)d_in[3];
    const int*   L = (const int*)d_in[4];
    int N = in_sizes[0] / DIM;

    float*          wsf     = (float*)d_ws;
    float*          sums    = wsf;
    int*            cpart   = (int*)(wsf + 8192);
    unsigned short* ncnh    = (unsigned short*)(wsf + 9216);
    float*          prg     = wsf + 13312;
    float*          cfg     = wsf + 13568;
    float*          ntv     = wsf + 13584;
    float*          tripart = wsf + 13600;   // 2048
    float*          atnpart = wsf + 15648;   // 1024

    k_init     <<<64,   256, 0, stream>>>(L, wsf, cpart, N);
    k_triplet  <<<2048, 256, 0, stream>>>(A, P, Q, tripart, N);
    k_segsum   <<<1024, 256, 0, stream>>>(E, L, sums, N);
    k_centroid <<<1,    256, 0, stream>>>(cpart, sums, ncnh, prg, cfg, ntv);
    k_atn      <<<512,  256, 0, stream>>>(E, L, ncnh, prg, cfg, atnpart, 512, N);
    k_final    <<<1,    256, 0, stream>>>(tripart, atnpart, ntv, (float*)d_out,
                                          1.f / (float)N, 2048, 512);
}

// Round 15
// 140.214 us; speedup vs baseline: 1.5385x; 1.0045x over previous
//
#include <hip/hip_runtime.h>

#define EPSN   1e-8f
#define MARGIN 0.2f
#define ALPHA  0.1f
#define BETA   1.05f
#define DIM    512
#define NCLS   16
#define NSTR   516

typedef __attribute__((ext_vector_type(8))) short short8;
typedef __attribute__((ext_vector_type(4))) float f32x4;
typedef __attribute__((ext_vector_type(4))) float nf4;

__device__ __forceinline__ unsigned short f2bf(float f) {
    unsigned u = __float_as_uint(f);
    return (unsigned short)((u + 0x7FFFu + ((u >> 16) & 1u)) >> 16);  // RNE
}
__device__ __forceinline__ short8 pack8(float4 x0, float4 x1) {
    short8 r;
    r[0] = (short)f2bf(x0.x); r[1] = (short)f2bf(x0.y);
    r[2] = (short)f2bf(x0.z); r[3] = (short)f2bf(x0.w);
    r[4] = (short)f2bf(x1.x); r[5] = (short)f2bf(x1.y);
    r[6] = (short)f2bf(x1.z); r[7] = (short)f2bf(x1.w);
    return r;
}

// ws layout (f32 words):
//     0: sums[8192]          8192: cpart i32[64][16]
//  9216: ncnh bf16[8192] (4096 words)    13312: pr[256]   13568: cf[16]   13584: ntv[2]
// 13600: tripart[1536]      15648: atnpart[1024]

// ---------------- Kernel 0: init = zero sums + label histogram partials ----------------
__global__ __launch_bounds__(256) void k_init(const int* __restrict__ L,
                                              float* __restrict__ wsw,
                                              int* __restrict__ cpart, int N) {
    __shared__ int hist[NCLS];
    int t = threadIdx.x, bid = blockIdx.x;
    int gid = bid * 256 + t;
    for (int i = gid; i < 8192; i += 64 * 256) wsw[i] = 0.f;
    if (t < NCLS) hist[t] = 0;
    __syncthreads();
    int chunk = N >> 6;
    int base = bid * chunk;
    for (int i = t * 4; i < chunk; i += 1024) {
        int4 l4 = *(const int4*)(L + base + i);
        atomicAdd(&hist[l4.x], 1);
        atomicAdd(&hist[l4.y], 1);
        atomicAdd(&hist[l4.z], 1);
        atomicAdd(&hist[l4.w], 1);
    }
    __syncthreads();
    if (t < NCLS) cpart[bid * NCLS + t] = hist[t];
}

// ---------------- Kernel 1: FUSED triplet + segsum ----------------
// (bid&3)==3 -> segsum (512 blocks, 256 rows each, half-column split, 16KB LDS).
// else      -> triplet (1536 blocks, R14 body, per-block partial stores).
// 16KB LDS keeps 8 blocks/CU (wave limit) — fixes R6's 33KB/4-blocks failure.
__global__ __launch_bounds__(256) void k_fused(const float* __restrict__ A,
                                               const float* __restrict__ P,
                                               const float* __restrict__ Q,
                                               const float* __restrict__ E,
                                               const int* __restrict__ L,
                                               float* __restrict__ sums,
                                               float* __restrict__ tripart, int N) {
    __shared__ float acc[NCLS * 256];   // 16 KB; triplet path uses acc[0..3]
    int t = threadIdx.x, lane = t & 63, wid = t >> 6;
    int bid = blockIdx.x;

    if ((bid & 3) == 3) {
        // ---------------- segsum path (512 blocks) ----------------
        int sb = bid >> 2;               // 0..511
        int half = sb & 1;
        int rg = sb >> 1;                // 0..255
        int rpg = N >> 8;                // 256 rows per block
        int r0 = rg * rpg;
        for (int i = t; i < NCLS * 256; i += 256) acc[i] = 0.f;
        __syncthreads();
        const float* Eh = E + half * 256 + t;
        for (int r = r0; r < r0 + rpg; r += 16) {
            int l[16];
            float v[16];
#pragma unroll
            for (int i = 0; i < 16; ++i) l[i] = L[r + i];
#pragma unroll
            for (int i = 0; i < 16; ++i) v[i] = Eh[(size_t)(r + i) * DIM];
#pragma unroll
            for (int i = 0; i < 16; ++i) acc[l[i] * 256 + t] += v[i];
        }
        __syncthreads();
#pragma unroll
        for (int c = 0; c < NCLS; ++c)
            atomicAdd(&sums[c * DIM + half * 256 + t], acc[c * 256 + t]);
    } else {
        // ---------------- triplet path (1536 blocks) ----------------
        int trank = bid - (bid >> 2);    // rank among triplet blocks
        const int NW = 1536 * 4;         // 6144 waves
        int g = lane >> 4, seg = lane & 15;
        int gw = trank * 4 + wid;
        int nquad = N >> 2;
        float tri = 0.f;
        for (int quad = gw; quad < nquad; quad += 2 * NW) {
            int quadB = quad + NW;
            bool hasB = quadB < nquad;
            size_t base0 = (size_t)(quad * 4 + g) * DIM + seg * 4;
            size_t base1 = hasB ? ((size_t)(quadB * 4 + g) * DIM + seg * 4) : base0;
            nf4 a0[8], p0[8], q0[8], a1[8], p1[8], q1[8];
#pragma unroll
            for (int i = 0; i < 8; ++i) a0[i] = __builtin_nontemporal_load((const nf4*)(A + base0 + i * 64));
#pragma unroll
            for (int i = 0; i < 8; ++i) p0[i] = __builtin_nontemporal_load((const nf4*)(P + base0 + i * 64));
#pragma unroll
            for (int i = 0; i < 8; ++i) q0[i] = __builtin_nontemporal_load((const nf4*)(Q + base0 + i * 64));
#pragma unroll
            for (int i = 0; i < 8; ++i) a1[i] = __builtin_nontemporal_load((const nf4*)(A + base1 + i * 64));
#pragma unroll
            for (int i = 0; i < 8; ++i) p1[i] = __builtin_nontemporal_load((const nf4*)(P + base1 + i * 64));
#pragma unroll
            for (int i = 0; i < 8; ++i) q1[i] = __builtin_nontemporal_load((const nf4*)(Q + base1 + i * 64));
            {
                float sa = 0, sp = 0, sn = 0, dap = 0, dan = 0;
#pragma unroll
                for (int i = 0; i < 8; ++i) {
                    sa  = fmaf(a0[i].x,a0[i].x, fmaf(a0[i].y,a0[i].y, fmaf(a0[i].z,a0[i].z, fmaf(a0[i].w,a0[i].w, sa))));
                    sp  = fmaf(p0[i].x,p0[i].x, fmaf(p0[i].y,p0[i].y, fmaf(p0[i].z,p0[i].z, fmaf(p0[i].w,p0[i].w, sp))));
                    sn  = fmaf(q0[i].x,q0[i].x, fmaf(q0[i].y,q0[i].y, fmaf(q0[i].z,q0[i].z, fmaf(q0[i].w,q0[i].w, sn))));
                    dap = fmaf(a0[i].x,p0[i].x, fmaf(a0[i].y,p0[i].y, fmaf(a0[i].z,p0[i].z, fmaf(a0[i].w,p0[i].w, dap))));
                    dan = fmaf(a0[i].x,q0[i].x, fmaf(a0[i].y,q0[i].y, fmaf(a0[i].z,q0[i].z, fmaf(a0[i].w,q0[i].w, dan))));
                }
#pragma unroll
                for (int o = 1; o < 16; o <<= 1) {
                    sa  += __shfl_xor(sa,  o);
                    sp  += __shfl_xor(sp,  o);
                    sn  += __shfl_xor(sn,  o);
                    dap += __shfl_xor(dap, o);
                    dan += __shfl_xor(dan, o);
                }
                if (seg == 0) {
                    float na = fmaxf(sqrtf(sa), EPSN);
                    float np = fmaxf(sqrtf(sp), EPSN);
                    float nn = fmaxf(sqrtf(sn), EPSN);
                    tri += fmaxf((1.f - dap / (na * np)) - (1.f - dan / (na * nn)) + MARGIN, 0.f);
                }
            }
            if (hasB) {
                float sa = 0, sp = 0, sn = 0, dap = 0, dan = 0;
#pragma unroll
                for (int i = 0; i < 8; ++i) {
                    sa  = fmaf(a1[i].x,a1[i].x, fmaf(a1[i].y,a1[i].y, fmaf(a1[i].z,a1[i].z, fmaf(a1[i].w,a1[i].w, sa))));
                    sp  = fmaf(p1[i].x,p1[i].x, fmaf(p1[i].y,p1[i].y, fmaf(p1[i].z,p1[i].z, fmaf(p1[i].w,p1[i].w, sp))));
                    sn  = fmaf(q1[i].x,q1[i].x, fmaf(q1[i].y,q1[i].y, fmaf(q1[i].z,q1[i].z, fmaf(q1[i].w,q1[i].w, sn))));
                    dap = fmaf(a1[i].x,p1[i].x, fmaf(a1[i].y,p1[i].y, fmaf(a1[i].z,p1[i].z, fmaf(a1[i].w,p1[i].w, dap))));
                    dan = fmaf(a1[i].x,q1[i].x, fmaf(a1[i].y,q1[i].y, fmaf(a1[i].z,q1[i].z, fmaf(a1[i].w,q1[i].w, dan))));
                }
#pragma unroll
                for (int o = 1; o < 16; o <<= 1) {
                    sa  += __shfl_xor(sa,  o);
                    sp  += __shfl_xor(sp,  o);
                    sn  += __shfl_xor(sn,  o);
                    dap += __shfl_xor(dap, o);
                    dan += __shfl_xor(dan, o);
                }
                if (seg == 0) {
                    float na = fmaxf(sqrtf(sa), EPSN);
                    float np = fmaxf(sqrtf(sp), EPSN);
                    float nn = fmaxf(sqrtf(sn), EPSN);
                    tri += fmaxf((1.f - dap / (na * np)) - (1.f - dan / (na * nn)) + MARGIN, 0.f);
                }
            }
        }
        tri += __shfl_xor(tri, 16);
        tri += __shfl_xor(tri, 32);
        if (lane == 0) acc[wid] = tri;
        __syncthreads();
        if (t == 0) tripart[trank] = acc[0] + acc[1] + acc[2] + acc[3];
    }
}

// ---------------- Kernel 2 (1 block): centroids, pair, cf, n_terms, bf16 centroids ----------------
__global__ __launch_bounds__(256) void k_centroid(const int* __restrict__ cpart,
                                                  const float* __restrict__ sums,
                                                  unsigned short* __restrict__ ncnh,
                                                  float* __restrict__ pr_g,
                                                  float* __restrict__ cf_g,
                                                  float* __restrict__ ntv) {
    __shared__ float ncns[NCLS * NSTR];
    __shared__ float prs[NCLS * NCLS];
    __shared__ float cntl[NCLS];
    int t = threadIdx.x;
    if (t < NCLS) {
        int s = 0;
        for (int b = 0; b < 64; ++b) s += cpart[b * NCLS + t];
        cntl[t] = (float)s;
    }
    __syncthreads();
    {
        int c = t >> 4, sI = t & 15;
        float inv = 1.f / fmaxf(cntl[c], 1.f);
        float4 v[8];
        float ssq = 0.f;
#pragma unroll
        for (int i = 0; i < 8; ++i) {
            v[i] = *(const float4*)(sums + c * DIM + sI * 32 + i * 4);
            v[i].x *= inv; v[i].y *= inv; v[i].z *= inv; v[i].w *= inv;
            ssq = fmaf(v[i].x, v[i].x, fmaf(v[i].y, v[i].y, fmaf(v[i].z, v[i].z, fmaf(v[i].w, v[i].w, ssq))));
        }
#pragma unroll
        for (int o = 1; o < 16; o <<= 1) ssq += __shfl_xor(ssq, o);
        float rs = 1.f / fmaxf(sqrtf(ssq), EPSN);
#pragma unroll
        for (int i = 0; i < 8; ++i) {
            float4 w = v[i];
            w.x *= rs; w.y *= rs; w.z *= rs; w.w *= rs;
            *(float4*)&ncns[c * NSTR + sI * 32 + i * 4] = w;
            ushort4 h;
            h.x = f2bf(w.x); h.y = f2bf(w.y); h.z = f2bf(w.z); h.w = f2bf(w.w);
            *(ushort4*)(ncnh + c * DIM + sI * 32 + i * 4) = h;
        }
    }
    __syncthreads();
    {
        int i = t >> 4, j = t & 15;
        float dot = 0.f;
        for (int d = 0; d < DIM; d += 4) {
            float4 a = *(const float4*)&ncns[i * NSTR + d];
            float4 b = *(const float4*)&ncns[j * NSTR + d];
            dot = fmaf(a.x, b.x, fmaf(a.y, b.y, fmaf(a.z, b.z, fmaf(a.w, b.w, dot))));
        }
        float cd = 1.f - dot;
        float pf = (cd <= BETA && i != j && cntl[i] > 0.f && cntl[j] > 0.f) ? 1.f : 0.f;
        prs[t] = pf;
        pr_g[t] = pf;
    }
    __syncthreads();
    if (t < NCLS) {
        float s = 0.f;
#pragma unroll
        for (int k = 0; k < NCLS; ++k) s += prs[t * 16 + k];
        cf_g[t] = s;
        cntl[t] = cntl[t] * s;
    }
    __syncthreads();
    if (t == 0) {
        float nt = 0.f;
#pragma unroll
        for (int k = 0; k < NCLS; ++k) nt += cntl[k];
        ntv[0] = nt;
        ntv[1] = 1.f / fmaxf(nt, 1.f);
    }
}

// ---------------- Kernel 3: ATN — LDS B-fragments, per-block partials ----------------
__global__ __launch_bounds__(256) void k_atn(const float* __restrict__ E,
                                             const int* __restrict__ L,
                                             const unsigned short* __restrict__ ncnh,
                                             const float* __restrict__ pr_g,
                                             const float* __restrict__ cf_g,
                                             float* __restrict__ atnpart,
                                             int nblk, int N) {
    __shared__ short bsh[16 * 4 * 16 * 8];   // 16 KB: [s][kg][col][8]
    __shared__ float pr[NCLS * NCLS];
    __shared__ float cf[NCLS];
    __shared__ float red[8];
    int t = threadIdx.x, lane = t & 63, wid = t >> 6;
    pr[t] = pr_g[t];
    if (t < NCLS) cf[t] = cf_g[t];
    {
        int ccol = t & 15, ckg = (t >> 4) & 3, sb = t >> 6;
#pragma unroll
        for (int i = 0; i < 4; ++i) {
            int s = sb * 4 + i;
            uint4 w = *(const uint4*)(ncnh + ccol * DIM + s * 32 + ckg * 8);
            *(uint4*)&bsh[((s * 4 + ckg) * 16 + ccol) * 8] = w;
        }
    }
    __syncthreads();

    int col = lane & 15;
    int kg = lane >> 4;
    const short* bbase = &bsh[(kg * 16 + col) * 8];

    float inter = 0.f, intra = 0.f;
    int gw = blockIdx.x * 4 + wid, nw = gridDim.x * 4;
    int ntile = N >> 4;
    for (int tile = gw; tile < ntile; tile += nw) {
        int rowb = tile << 4;
        int lval = L[rowb + col];
        const float* ar = E + (size_t)(rowb + col) * DIM + kg * 8;
        f32x4 ac0 = {0,0,0,0}, ac1 = {0,0,0,0}, ac2 = {0,0,0,0}, ac3 = {0,0,0,0};
        float ss0 = 0.f, ss1 = 0.f, ss2 = 0.f, ss3 = 0.f;
#pragma unroll
        for (int sg = 0; sg < 4; ++sg) {
            float4 x[8];
#pragma unroll
            for (int k = 0; k < 8; ++k)
                x[k] = *(const float4*)(ar + sg * 128 + (k >> 1) * 32 + (k & 1) * 4);
            {
                float4 u = x[0], v = x[1];
                short8 bf = *(const short8*)(bbase + (sg * 4 + 0) * 512);
                ss0 = fmaf(u.x,u.x, fmaf(u.y,u.y, fmaf(u.z,u.z, fmaf(u.w,u.w, ss0))));
                ss0 = fmaf(v.x,v.x, fmaf(v.y,v.y, fmaf(v.z,v.z, fmaf(v.w,v.w, ss0))));
                ac0 = __builtin_amdgcn_mfma_f32_16x16x32_bf16(pack8(u, v), bf, ac0, 0, 0, 0);
            }
            {
                float4 u = x[2], v = x[3];
                short8 bf = *(const short8*)(bbase + (sg * 4 + 1) * 512);
                ss1 = fmaf(u.x,u.x, fmaf(u.y,u.y, fmaf(u.z,u.z, fmaf(u.w,u.w, ss1))));
                ss1 = fmaf(v.x,v.x, fmaf(v.y,v.y, fmaf(v.z,v.z, fmaf(v.w,v.w, ss1))));
                ac1 = __builtin_amdgcn_mfma_f32_16x16x32_bf16(pack8(u, v), bf, ac1, 0, 0, 0);
            }
            {
                float4 u = x[4], v = x[5];
                short8 bf = *(const short8*)(bbase + (sg * 4 + 2) * 512);
                ss2 = fmaf(u.x,u.x, fmaf(u.y,u.y, fmaf(u.z,u.z, fmaf(u.w,u.w, ss2))));
                ss2 = fmaf(v.x,v.x, fmaf(v.y,v.y, fmaf(v.z,v.z, fmaf(v.w,v.w, ss2))));
                ac2 = __builtin_amdgcn_mfma_f32_16x16x32_bf16(pack8(u, v), bf, ac2, 0, 0, 0);
            }
            {
                float4 u = x[6], v = x[7];
                short8 bf = *(const short8*)(bbase + (sg * 4 + 3) * 512);
                ss3 = fmaf(u.x,u.x, fmaf(u.y,u.y, fmaf(u.z,u.z, fmaf(u.w,u.w, ss3))));
                ss3 = fmaf(v.x,v.x, fmaf(v.y,v.y, fmaf(v.z,v.z, fmaf(v.w,v.w, ss3))));
                ac3 = __builtin_amdgcn_mfma_f32_16x16x32_bf16(pack8(u, v), bf, ac3, 0, 0, 0);
            }
        }
        f32x4 accv = (ac0 + ac1) + (ac2 + ac3);
        float ss = (ss0 + ss1) + (ss2 + ss3);
        ss += __shfl_xor(ss, 16);
        ss += __shfl_xor(ss, 32);
#pragma unroll
        for (int reg = 0; reg < 4; ++reg) {
            int row = kg * 4 + reg;
            float s2 = __shfl(ss, row);
            int lab = __shfl(lval, row);
            float rinv = 1.f / fmaxf(sqrtf(s2), EPSN);
            float d = 1.f - accv[reg] * rinv;
            inter += pr[lab * 16 + col] * fmaxf(BETA - d, 0.f);
            if (col == lab) intra += cf[lab] * fmaxf(d - ALPHA, 0.f);
        }
    }
#pragma unroll
    for (int o = 32; o > 0; o >>= 1) {
        inter += __shfl_xor(inter, o);
        intra += __shfl_xor(intra, o);
    }
    if (lane == 0) { red[wid] = intra; red[4 + wid] = inter; }
    __syncthreads();
    if (t == 0) {
        atnpart[blockIdx.x]        = red[0] + red[1] + red[2] + red[3];
        atnpart[nblk + blockIdx.x] = red[4] + red[5] + red[6] + red[7];
    }
}

// ---------------- Kernel 4 (1 block): final reduction ----------------
__global__ __launch_bounds__(256) void k_final(const float* __restrict__ tripart,
                                               const float* __restrict__ atnpart,
                                               const float* __restrict__ ntv,
                                               float* __restrict__ out,
                                               float invN, int ntri, int natn) {
    __shared__ float r[12];
    int t = threadIdx.x, lane = t & 63, wid = t >> 6;
    float s_tri = 0.f, s_in = 0.f, s_ie = 0.f;
    for (int i = t; i < ntri; i += 256) s_tri += tripart[i];
    for (int i = t; i < natn; i += 256) { s_in += atnpart[i]; s_ie += atnpart[natn + i]; }
#pragma unroll
    for (int o = 1; o < 64; o <<= 1) {
        s_tri += __shfl_xor(s_tri, o);
        s_in  += __shfl_xor(s_in,  o);
        s_ie  += __shfl_xor(s_ie,  o);
    }
    if (lane == 0) { r[wid] = s_tri; r[4 + wid] = s_in; r[8 + wid] = s_ie; }
    __syncthreads();
    if (t == 0) {
        float tri = r[0] + r[1] + r[2] + r[3];
        float in2 = r[4] + r[5] + r[6] + r[7];
        float ie2 = r[8] + r[9] + r[10] + r[11];
        float nt = ntv[0];
        float atnv = (nt > 0.f) ? (in2 + ie2) * ntv[1] : 0.f;
        out[0] = tri * invN + atnv;
    }
}

extern "C" void kernel_launch(void* const* d_in, const int* in_sizes, int n_in,
                              void* d_out, int out_size, void* d_ws, size_t ws_size,
                              hipStream_t stream) {
    const float* A = (const float*)d_in[0];
    const float* P = (const float*)d_in[1];
    const float* Q = (const float*)d_in[2];
    const float* E = (const float*)d_in[3];
    const int*   L = (const int*)d_in[4];
    int N = in_sizes[0] / DIM;

    float*          wsf     = (float*)d_ws;
    float*          sums    = wsf;
    int*            cpart   = (int*)(wsf + 8192);
    unsigned short* ncnh    = (unsigned short*)(wsf + 9216);
    float*          prg     = wsf + 13312;
    float*          cfg     = wsf + 13568;
    float*          ntv     = wsf + 13584;
    float*          tripart = wsf + 13600;   // 1536
    float*          atnpart = wsf + 15648;   // 1024

    k_init     <<<64,   256, 0, stream>>>(L, wsf, cpart, N);
    k_fused    <<<2048, 256, 0, stream>>>(A, P, Q, E, L, sums, tripart, N);
    k_centroid <<<1,    256, 0, stream>>>(cpart, sums, ncnh, prg, cfg, ntv);
    k_atn      <<<512,  256, 0, stream>>>(E, L, ncnh, prg, cfg, atnpart, 512, N);
    k_final    <<<1,    256, 0, stream>>>(tripart, atnpart, ntv, (float*)d_out,
                                          1.f / (float)N, 1536, 512);
}

// Round 16
// 137.770 us; speedup vs baseline: 1.5658x; 1.0177x over previous
//
#include <hip/hip_runtime.h>

#define EPSN   1e-8f
#define MARGIN 0.2f
#define ALPHA  0.1f
#define BETA   1.05f
#define DIM    512
#define NCLS   16
#define NSTR   516

typedef __attribute__((ext_vector_type(8))) short short8;
typedef __attribute__((ext_vector_type(4))) float f32x4;
typedef __attribute__((ext_vector_type(4))) float nf4;

__device__ __forceinline__ unsigned short f2bf(float f) {
    unsigned u = __float_as_uint(f);
    return (unsigned short)((u + 0x7FFFu + ((u >> 16) & 1u)) >> 16);  // RNE
}
__device__ __forceinline__ short8 pack8(float4 x0, float4 x1) {
    short8 r;
    r[0] = (short)f2bf(x0.x); r[1] = (short)f2bf(x0.y);
    r[2] = (short)f2bf(x0.z); r[3] = (short)f2bf(x0.w);
    r[4] = (short)f2bf(x1.x); r[5] = (short)f2bf(x1.y);
    r[6] = (short)f2bf(x1.z); r[7] = (short)f2bf(x1.w);
    return r;
}

// ws layout (f32 words):
//     0: sums[8192]          8192: cpart i32[64][16]
//  9216: ncnh bf16[8192] (4096 words)    13312: pr[256]   13568: cf[16]   13584: ntv[2]
// 13600: tripart[2048]      15648: atnpart[2048]

// ---------------- Kernel 1: triplet (+ init prelude on blocks 0-63) ----------------
// Blocks 0..63 first zero sums and write label-histogram partials (cheap, disjoint
// arrays), then join the triplet work. segsum launches after this kernel completes.
__global__ __launch_bounds__(256) void k_triplet(const float* __restrict__ A,
                                                 const float* __restrict__ P,
                                                 const float* __restrict__ Q,
                                                 const int* __restrict__ L,
                                                 float* __restrict__ wsw,
                                                 int* __restrict__ cpart,
                                                 float* __restrict__ tripart, int N) {
    __shared__ float red[4];
    __shared__ int hist[NCLS];
    int t = threadIdx.x, lane = t & 63, wid = t >> 6;
    int bid = blockIdx.x;

    if (bid < 64) {   // ---- init prelude ----
        int gid = bid * 256 + t;
        for (int i = gid; i < 8192; i += 64 * 256) wsw[i] = 0.f;
        if (t < NCLS) hist[t] = 0;
        __syncthreads();
        int chunk = N >> 6;
        int base = bid * chunk;
        for (int i = t * 4; i < chunk; i += 1024) {
            int4 l4 = *(const int4*)(L + base + i);
            atomicAdd(&hist[l4.x], 1);
            atomicAdd(&hist[l4.y], 1);
            atomicAdd(&hist[l4.z], 1);
            atomicAdd(&hist[l4.w], 1);
        }
        __syncthreads();
        if (t < NCLS) cpart[bid * NCLS + t] = hist[t];
        __syncthreads();
    }

    int g = lane >> 4, seg = lane & 15;
    int gw = bid * 4 + wid, nw = gridDim.x * 4;
    int nquad = N >> 2;
    float tri = 0.f;
    for (int quad = gw; quad < nquad; quad += 2 * nw) {
        int quadB = quad + nw;
        bool hasB = quadB < nquad;
        size_t base0 = (size_t)(quad * 4 + g) * DIM + seg * 4;
        size_t base1 = hasB ? ((size_t)(quadB * 4 + g) * DIM + seg * 4) : base0;
        nf4 a0[8], p0[8], q0[8], a1[8], p1[8], q1[8];
#pragma unroll
        for (int i = 0; i < 8; ++i) a0[i] = __builtin_nontemporal_load((const nf4*)(A + base0 + i * 64));
#pragma unroll
        for (int i = 0; i < 8; ++i) p0[i] = __builtin_nontemporal_load((const nf4*)(P + base0 + i * 64));
#pragma unroll
        for (int i = 0; i < 8; ++i) q0[i] = __builtin_nontemporal_load((const nf4*)(Q + base0 + i * 64));
#pragma unroll
        for (int i = 0; i < 8; ++i) a1[i] = __builtin_nontemporal_load((const nf4*)(A + base1 + i * 64));
#pragma unroll
        for (int i = 0; i < 8; ++i) p1[i] = __builtin_nontemporal_load((const nf4*)(P + base1 + i * 64));
#pragma unroll
        for (int i = 0; i < 8; ++i) q1[i] = __builtin_nontemporal_load((const nf4*)(Q + base1 + i * 64));
        {
            float sa = 0, sp = 0, sn = 0, dap = 0, dan = 0;
#pragma unroll
            for (int i = 0; i < 8; ++i) {
                sa  = fmaf(a0[i].x,a0[i].x, fmaf(a0[i].y,a0[i].y, fmaf(a0[i].z,a0[i].z, fmaf(a0[i].w,a0[i].w, sa))));
                sp  = fmaf(p0[i].x,p0[i].x, fmaf(p0[i].y,p0[i].y, fmaf(p0[i].z,p0[i].z, fmaf(p0[i].w,p0[i].w, sp))));
                sn  = fmaf(q0[i].x,q0[i].x, fmaf(q0[i].y,q0[i].y, fmaf(q0[i].z,q0[i].z, fmaf(q0[i].w,q0[i].w, sn))));
                dap = fmaf(a0[i].x,p0[i].x, fmaf(a0[i].y,p0[i].y, fmaf(a0[i].z,p0[i].z, fmaf(a0[i].w,p0[i].w, dap))));
                dan = fmaf(a0[i].x,q0[i].x, fmaf(a0[i].y,q0[i].y, fmaf(a0[i].z,q0[i].z, fmaf(a0[i].w,q0[i].w, dan))));
            }
#pragma unroll
            for (int o = 1; o < 16; o <<= 1) {
                sa  += __shfl_xor(sa,  o);
                sp  += __shfl_xor(sp,  o);
                sn  += __shfl_xor(sn,  o);
                dap += __shfl_xor(dap, o);
                dan += __shfl_xor(dan, o);
            }
            if (seg == 0) {
                float na = fmaxf(sqrtf(sa), EPSN);
                float np = fmaxf(sqrtf(sp), EPSN);
                float nn = fmaxf(sqrtf(sn), EPSN);
                tri += fmaxf((1.f - dap / (na * np)) - (1.f - dan / (na * nn)) + MARGIN, 0.f);
            }
        }
        if (hasB) {
            float sa = 0, sp = 0, sn = 0, dap = 0, dan = 0;
#pragma unroll
            for (int i = 0; i < 8; ++i) {
                sa  = fmaf(a1[i].x,a1[i].x, fmaf(a1[i].y,a1[i].y, fmaf(a1[i].z,a1[i].z, fmaf(a1[i].w,a1[i].w, sa))));
                sp  = fmaf(p1[i].x,p1[i].x, fmaf(p1[i].y,p1[i].y, fmaf(p1[i].z,p1[i].z, fmaf(p1[i].w,p1[i].w, sp))));
                sn  = fmaf(q1[i].x,q1[i].x, fmaf(q1[i].y,q1[i].y, fmaf(q1[i].z,q1[i].z, fmaf(q1[i].w,q1[i].w, sn))));
                dap = fmaf(a1[i].x,p1[i].x, fmaf(a1[i].y,p1[i].y, fmaf(a1[i].z,p1[i].z, fmaf(a1[i].w,p1[i].w, dap))));
                dan = fmaf(a1[i].x,q1[i].x, fmaf(a1[i].y,q1[i].y, fmaf(a1[i].z,q1[i].z, fmaf(a1[i].w,q1[i].w, dan))));
            }
#pragma unroll
            for (int o = 1; o < 16; o <<= 1) {
                sa  += __shfl_xor(sa,  o);
                sp  += __shfl_xor(sp,  o);
                sn  += __shfl_xor(sn,  o);
                dap += __shfl_xor(dap, o);
                dan += __shfl_xor(dan, o);
            }
            if (seg == 0) {
                float na = fmaxf(sqrtf(sa), EPSN);
                float np = fmaxf(sqrtf(sp), EPSN);
                float nn = fmaxf(sqrtf(sn), EPSN);
                tri += fmaxf((1.f - dap / (na * np)) - (1.f - dan / (na * nn)) + MARGIN, 0.f);
            }
        }
    }
    tri += __shfl_xor(tri, 16);
    tri += __shfl_xor(tri, 32);
    if (lane == 0) red[wid] = tri;
    __syncthreads();
    if (t == 0) tripart[bid] = red[0] + red[1] + red[2] + red[3];
}

// ---------------- Kernel 2: per-class sums (R10/R14 form) ----------------
__global__ __launch_bounds__(256) void k_segsum(const float* __restrict__ E,
                                                const int* __restrict__ L,
                                                float* __restrict__ sums, int N) {
    __shared__ float acc[NCLS * 256];    // exactly 16 KB
    int t = threadIdx.x;
    int half = blockIdx.x & 1;
    int rg = blockIdx.x >> 1;
    int rpg = N >> 9;
    int r0 = rg * rpg;
    for (int i = t; i < NCLS * 256; i += 256) acc[i] = 0.f;
    __syncthreads();
    const float* Eh = E + half * 256 + t;
    for (int r = r0; r < r0 + rpg; r += 16) {
        int l[16];
        float v[16];
#pragma unroll
        for (int i = 0; i < 16; ++i) l[i] = L[r + i];
#pragma unroll
        for (int i = 0; i < 16; ++i) v[i] = Eh[(size_t)(r + i) * DIM];
#pragma unroll
        for (int i = 0; i < 16; ++i) acc[l[i] * 256 + t] += v[i];
    }
    __syncthreads();
#pragma unroll
    for (int c = 0; c < NCLS; ++c)
        atomicAdd(&sums[c * DIM + half * 256 + t], acc[c * 256 + t]);
}

// ---------------- Kernel 3 (1 block): centroids, pair, cf, n_terms, bf16 centroids ----------------
__global__ __launch_bounds__(256) void k_centroid(const int* __restrict__ cpart,
                                                  const float* __restrict__ sums,
                                                  unsigned short* __restrict__ ncnh,
                                                  float* __restrict__ pr_g,
                                                  float* __restrict__ cf_g,
                                                  float* __restrict__ ntv) {
    __shared__ float ncns[NCLS * NSTR];
    __shared__ float prs[NCLS * NCLS];
    __shared__ float cntl[NCLS];
    int t = threadIdx.x;
    if (t < NCLS) {
        int s = 0;
        for (int b = 0; b < 64; ++b) s += cpart[b * NCLS + t];
        cntl[t] = (float)s;
    }
    __syncthreads();
    {
        int c = t >> 4, sI = t & 15;
        float inv = 1.f / fmaxf(cntl[c], 1.f);
        float4 v[8];
        float ssq = 0.f;
#pragma unroll
        for (int i = 0; i < 8; ++i) {
            v[i] = *(const float4*)(sums + c * DIM + sI * 32 + i * 4);
            v[i].x *= inv; v[i].y *= inv; v[i].z *= inv; v[i].w *= inv;
            ssq = fmaf(v[i].x, v[i].x, fmaf(v[i].y, v[i].y, fmaf(v[i].z, v[i].z, fmaf(v[i].w, v[i].w, ssq))));
        }
#pragma unroll
        for (int o = 1; o < 16; o <<= 1) ssq += __shfl_xor(ssq, o);
        float rs = 1.f / fmaxf(sqrtf(ssq), EPSN);
#pragma unroll
        for (int i = 0; i < 8; ++i) {
            float4 w = v[i];
            w.x *= rs; w.y *= rs; w.z *= rs; w.w *= rs;
            *(float4*)&ncns[c * NSTR + sI * 32 + i * 4] = w;
            ushort4 h;
            h.x = f2bf(w.x); h.y = f2bf(w.y); h.z = f2bf(w.z); h.w = f2bf(w.w);
            *(ushort4*)(ncnh + c * DIM + sI * 32 + i * 4) = h;
        }
    }
    __syncthreads();
    {
        int i = t >> 4, j = t & 15;
        float dot = 0.f;
        for (int d = 0; d < DIM; d += 4) {
            float4 a = *(const float4*)&ncns[i * NSTR + d];
            float4 b = *(const float4*)&ncns[j * NSTR + d];
            dot = fmaf(a.x, b.x, fmaf(a.y, b.y, fmaf(a.z, b.z, fmaf(a.w, b.w, dot))));
        }
        float cd = 1.f - dot;
        float pf = (cd <= BETA && i != j && cntl[i] > 0.f && cntl[j] > 0.f) ? 1.f : 0.f;
        prs[t] = pf;
        pr_g[t] = pf;
    }
    __syncthreads();
    if (t < NCLS) {
        float s = 0.f;
#pragma unroll
        for (int k = 0; k < NCLS; ++k) s += prs[t * 16 + k];
        cf_g[t] = s;
        cntl[t] = cntl[t] * s;
    }
    __syncthreads();
    if (t == 0) {
        float nt = 0.f;
#pragma unroll
        for (int k = 0; k < NCLS; ++k) nt += cntl[k];
        ntv[0] = nt;
        ntv[1] = 1.f / fmaxf(nt, 1.f);
    }
}

// ---------------- Kernel 4: ATN — LDS B-fragments, per-block partials ----------------
__global__ __launch_bounds__(256) void k_atn(const float* __restrict__ E,
                                             const int* __restrict__ L,
                                             const unsigned short* __restrict__ ncnh,
                                             const float* __restrict__ pr_g,
                                             const float* __restrict__ cf_g,
                                             float* __restrict__ atnpart,
                                             int nblk, int N) {
    __shared__ short bsh[16 * 4 * 16 * 8];   // 16 KB: [s][kg][col][8]
    __shared__ float pr[NCLS * NCLS];
    __shared__ float cf[NCLS];
    __shared__ float red[8];
    int t = threadIdx.x, lane = t & 63, wid = t >> 6;
    pr[t] = pr_g[t];
    if (t < NCLS) cf[t] = cf_g[t];
    {
        int ccol = t & 15, ckg = (t >> 4) & 3, sb = t >> 6;
#pragma unroll
        for (int i = 0; i < 4; ++i) {
            int s = sb * 4 + i;
            uint4 w = *(const uint4*)(ncnh + ccol * DIM + s * 32 + ckg * 8);
            *(uint4*)&bsh[((s * 4 + ckg) * 16 + ccol) * 8] = w;
        }
    }
    __syncthreads();

    int col = lane & 15;
    int kg = lane >> 4;
    const short* bbase = &bsh[(kg * 16 + col) * 8];

    float inter = 0.f, intra = 0.f;
    int gw = blockIdx.x * 4 + wid, nw = gridDim.x * 4;
    int ntile = N >> 4;
    for (int tile = gw; tile < ntile; tile += nw) {
        int rowb = tile << 4;
        int lval = L[rowb + col];
        const float* ar = E + (size_t)(rowb + col) * DIM + kg * 8;
        f32x4 ac0 = {0,0,0,0}, ac1 = {0,0,0,0}, ac2 = {0,0,0,0}, ac3 = {0,0,0,0};
        float ss0 = 0.f, ss1 = 0.f, ss2 = 0.f, ss3 = 0.f;
#pragma unroll
        for (int sg = 0; sg < 4; ++sg) {
            float4 x[8];
#pragma unroll
            for (int k = 0; k < 8; ++k)
                x[k] = *(const float4*)(ar + sg * 128 + (k >> 1) * 32 + (k & 1) * 4);
            {
                float4 u = x[0], v = x[1];
                short8 bf = *(const short8*)(bbase + (sg * 4 + 0) * 512);
                ss0 = fmaf(u.x,u.x, fmaf(u.y,u.y, fmaf(u.z,u.z, fmaf(u.w,u.w, ss0))));
                ss0 = fmaf(v.x,v.x, fmaf(v.y,v.y, fmaf(v.z,v.z, fmaf(v.w,v.w, ss0))));
                ac0 = __builtin_amdgcn_mfma_f32_16x16x32_bf16(pack8(u, v), bf, ac0, 0, 0, 0);
            }
            {
                float4 u = x[2], v = x[3];
                short8 bf = *(const short8*)(bbase + (sg * 4 + 1) * 512);
                ss1 = fmaf(u.x,u.x, fmaf(u.y,u.y, fmaf(u.z,u.z, fmaf(u.w,u.w, ss1))));
                ss1 = fmaf(v.x,v.x, fmaf(v.y,v.y, fmaf(v.z,v.z, fmaf(v.w,v.w, ss1))));
                ac1 = __builtin_amdgcn_mfma_f32_16x16x32_bf16(pack8(u, v), bf, ac1, 0, 0, 0);
            }
            {
                float4 u = x[4], v = x[5];
                short8 bf = *(const short8*)(bbase + (sg * 4 + 2) * 512);
                ss2 = fmaf(u.x,u.x, fmaf(u.y,u.y, fmaf(u.z,u.z, fmaf(u.w,u.w, ss2))));
                ss2 = fmaf(v.x,v.x, fmaf(v.y,v.y, fmaf(v.z,v.z, fmaf(v.w,v.w, ss2))));
                ac2 = __builtin_amdgcn_mfma_f32_16x16x32_bf16(pack8(u, v), bf, ac2, 0, 0, 0);
            }
            {
                float4 u = x[6], v = x[7];
                short8 bf = *(const short8*)(bbase + (sg * 4 + 3) * 512);
                ss3 = fmaf(u.x,u.x, fmaf(u.y,u.y, fmaf(u.z,u.z, fmaf(u.w,u.w, ss3))));
                ss3 = fmaf(v.x,v.x, fmaf(v.y,v.y, fmaf(v.z,v.z, fmaf(v.w,v.w, ss3))));
                ac3 = __builtin_amdgcn_mfma_f32_16x16x32_bf16(pack8(u, v), bf, ac3, 0, 0, 0);
            }
        }
        f32x4 accv = (ac0 + ac1) + (ac2 + ac3);
        float ss = (ss0 + ss1) + (ss2 + ss3);
        ss += __shfl_xor(ss, 16);
        ss += __shfl_xor(ss, 32);
#pragma unroll
        for (int reg = 0; reg < 4; ++reg) {
            int row = kg * 4 + reg;
            float s2 = __shfl(ss, row);
            int lab = __shfl(lval, row);
            float rinv = 1.f / fmaxf(sqrtf(s2), EPSN);
            float d = 1.f - accv[reg] * rinv;
            inter += pr[lab * 16 + col] * fmaxf(BETA - d, 0.f);
            if (col == lab) intra += cf[lab] * fmaxf(d - ALPHA, 0.f);
        }
    }
#pragma unroll
    for (int o = 32; o > 0; o >>= 1) {
        inter += __shfl_xor(inter, o);
        intra += __shfl_xor(intra, o);
    }
    if (lane == 0) { red[wid] = intra; red[4 + wid] = inter; }
    __syncthreads();
    if (t == 0) {
        atnpart[blockIdx.x]        = red[0] + red[1] + red[2] + red[3];
        atnpart[nblk + blockIdx.x] = red[4] + red[5] + red[6] + red[7];
    }
}

// ---------------- Kernel 5 (1 block): final reduction ----------------
__global__ __launch_bounds__(256) void k_final(const float* __restrict__ tripart,
                                               const float* __restrict__ atnpart,
                                               const float* __restrict__ ntv,
                                               float* __restrict__ out,
                                               float invN, int ntri, int natn) {
    __shared__ float r[12];
    int t = threadIdx.x, lane = t & 63, wid = t >> 6;
    float s_tri = 0.f, s_in = 0.f, s_ie = 0.f;
    for (int i = t; i < ntri; i += 256) s_tri += tripart[i];
    for (int i = t; i < natn; i += 256) { s_in += atnpart[i]; s_ie += atnpart[natn + i]; }
#pragma unroll
    for (int o = 1; o < 64; o <<= 1) {
        s_tri += __shfl_xor(s_tri, o);
        s_in  += __shfl_xor(s_in,  o);
        s_ie  += __shfl_xor(s_ie,  o);
    }
    if (lane == 0) { r[wid] = s_tri; r[4 + wid] = s_in; r[8 + wid] = s_ie; }
    __syncthreads();
    if (t == 0) {
        float tri = r[0] + r[1] + r[2] + r[3];
        float in2 = r[4] + r[5] + r[6] + r[7];
        float ie2 = r[8] + r[9] + r[10] + r[11];
        float nt = ntv[0];
        float atnv = (nt > 0.f) ? (in2 + ie2) * ntv[1] : 0.f;
        out[0] = tri * invN + atnv;
    }
}

extern "C" void kernel_launch(void* const* d_in, const int* in_sizes, int n_in,
                              void* d_out, int out_size, void* d_ws, size_t ws_size,
                              hipStream_t stream) {
    const float* A = (const float*)d_in[0];
    const float* P = (const float*)d_in[1];
    const float* Q = (const float*)d_in[2];
    const float* E = (const float*)d_in[3];
    const int*   L = (const int*)d_in[4];
    int N = in_sizes[0] / DIM;

    float*          wsf     = (float*)d_ws;
    float*          sums    = wsf;
    int*            cpart   = (int*)(wsf + 8192);
    unsigned short* ncnh    = (unsigned short*)(wsf + 9216);
    float*          prg     = wsf + 13312;
    float*          cfg     = wsf + 13568;
    float*          ntv     = wsf + 13584;
    float*          tripart = wsf + 13600;   // 2048
    float*          atnpart = wsf + 15648;   // 2048

    k_triplet  <<<2048, 256, 0, stream>>>(A, P, Q, L, wsf, cpart, tripart, N);
    k_segsum   <<<1024, 256, 0, stream>>>(E, L, sums, N);
    k_centroid <<<1,    256, 0, stream>>>(cpart, sums, ncnh, prg, cfg, ntv);
    k_atn      <<<1024, 256, 0, stream>>>(E, L, ncnh, prg, cfg, atnpart, 1024, N);
    k_final    <<<1,    256, 0, stream>>>(tripart, atnpart, ntv, (float*)d_out,
                                          1.f / (float)N, 2048, 1024);
}